// Round 1
// baseline (2316.048 us; speedup 1.0000x reference)
//
#include <hip/hip_runtime.h>
#include <math.h>

#define MAXN_P 0.996f   // (1 - PROJ_EPS)/sqrt(c), c=1

__device__ __forceinline__ float wred(float v){
  #pragma unroll
  for(int o=32;o>0;o>>=1) v += __shfl_xor(v,o,64);
  return v;
}
__device__ __forceinline__ float artanh_c(float x){
  x = fminf(x, 1.0f-1e-7f);
  x = fmaxf(x, -1.0f+1e-7f);
  return atanhf(x);
}

// ---------------- CSR build ----------------
__global__ void k_hist(const int* __restrict__ dst, int* __restrict__ cnt, int E){
  int e = blockIdx.x*blockDim.x + threadIdx.x;
  if (e < E) atomicAdd(&cnt[dst[e]], 1);
}

__global__ void k_scan(const int* __restrict__ cnt, int* __restrict__ rowptr,
                       int* __restrict__ cursor, int N){
  __shared__ int sh[1024];
  int t = threadIdx.x;
  int chunk = (N + 1023) / 1024;
  int b = t*chunk;
  int e = b + chunk; if (e > N) e = N;
  int s = 0;
  for(int i=b;i<e && i<N;i++) s += cnt[i];
  sh[t] = s;
  __syncthreads();
  for(int off=1; off<1024; off<<=1){
    int add = (t>=off) ? sh[t-off] : 0;
    __syncthreads();
    sh[t] += add;
    __syncthreads();
  }
  int run = (t==0) ? 0 : sh[t-1];
  for(int i=b;i<e && i<N;i++){
    rowptr[i] = run; cursor[i] = run; run += cnt[i];
  }
  if (t == 1023) rowptr[N] = run;
}

__global__ void k_fill(const int* __restrict__ src, const int* __restrict__ dst,
                       int* __restrict__ cursor, int2* __restrict__ se, int E){
  int e = blockIdx.x*blockDim.x + threadIdx.x;
  if (e >= E) return;
  int d = dst[e];
  int pos = atomicAdd(&cursor[d], 1);
  se[pos] = make_int2(src[e], e);
}

// ---------------- rowwise: h0 = proj(expmap0(x)), n0 = ||h0|| ----------------
__global__ void k_exp0(const float* __restrict__ x, float* __restrict__ h0,
                       float* __restrict__ n0, int N){
  int wid = (blockIdx.x*blockDim.x + threadIdx.x)>>6;
  int lane = threadIdx.x & 63;
  if (wid >= N) return;
  const float* r = x + (size_t)wid*128;
  float u0 = r[lane], u1 = r[lane+64];
  float ss = wred(u0*u0 + u1*u1);
  float un = fmaxf(sqrtf(ss), 1e-15f);
  float tn = tanhf(un);
  float sc = tn/un;
  float pn = tn;
  if (pn > MAXN_P){ sc *= MAXN_P/pn; pn = MAXN_P; }
  h0[(size_t)wid*128 + lane]      = u0*sc;
  h0[(size_t)wid*128 + lane + 64] = u1*sc;
  if (lane == 0) n0[wid] = pn;
}

// ---------------- hb = proj(expmap0(b)) for 4 branches x 2 layers ----------------
__global__ void k_hb(const float* __restrict__ b0, const float* __restrict__ b1,
                     float* __restrict__ hb0, float* __restrict__ hb1,
                     int HID, int DIM){
  int bl = blockIdx.x;       // 0..7
  int lane = threadIdx.x;    // 64
  int layer = bl >> 2, br = bl & 3;
  int D = layer ? DIM : HID;
  const float* b = layer ? (b1 + (size_t)br*DIM) : (b0 + (size_t)br*HID);
  float* o       = layer ? (hb1 + (size_t)br*DIM) : (hb0 + (size_t)br*HID);
  float v0 = (lane < D) ? b[lane] : 0.f;
  float v1 = (lane+64 < D) ? b[lane+64] : 0.f;
  float ss = wred(v0*v0 + v1*v1);
  float n = fmaxf(sqrtf(ss), 1e-15f);
  float tn = tanhf(n);
  float sc = tn/n;
  if (tn > MAXN_P) sc *= MAXN_P/tn;
  if (lane < D)    o[lane]    = v0*sc;
  if (lane+64 < D) o[lane+64] = v1*sc;
}

// ---------------- f32 GEMM: C[M,J] = A[M,128] * W[J,128]^T ----------------
__global__ __launch_bounds__(256) void k_gemm(const float* __restrict__ A,
                                              const float* __restrict__ W,
                                              float* __restrict__ Cmat,
                                              int M, int J){
  __shared__ float Al[64*68];
  __shared__ float Wl[64*68];
  int rb = blockIdx.x*64;
  int cb = blockIdx.y*64;
  int t = threadIdx.x;
  int tr = t >> 4, tc = t & 15;
  float acc[4][4] = {};
  for(int kk=0; kk<128; kk+=64){
    // stage A tile: 64 rows x 64 k = 1024 float4
    #pragma unroll
    for(int i=0;i<4;i++){
      int idx = t + i*256;
      int r = idx>>4, k4 = idx&15;
      float4 v = make_float4(0,0,0,0);
      int gr = rb + r;
      if (gr < M) v = *(const float4*)(A + (size_t)gr*128 + kk + k4*4);
      *(float4*)(Al + r*68 + k4*4) = v;
    }
    #pragma unroll
    for(int i=0;i<4;i++){
      int idx = t + i*256;
      int r = idx>>4, k4 = idx&15;
      float4 v = *(const float4*)(W + (size_t)(cb + r)*128 + kk + k4*4);
      *(float4*)(Wl + r*68 + k4*4) = v;
    }
    __syncthreads();
    #pragma unroll
    for(int k=0;k<64;k+=4){
      float4 a[4], b[4];
      #pragma unroll
      for(int i=0;i<4;i++) a[i] = *(float4*)(Al + (tr+16*i)*68 + k);
      #pragma unroll
      for(int i=0;i<4;i++) b[i] = *(float4*)(Wl + (tc+16*i)*68 + k);
      #pragma unroll
      for(int i=0;i<4;i++)
        #pragma unroll
        for(int j=0;j<4;j++){
          acc[i][j] = fmaf(a[i].x, b[j].x, acc[i][j]);
          acc[i][j] = fmaf(a[i].y, b[j].y, acc[i][j]);
          acc[i][j] = fmaf(a[i].z, b[j].z, acc[i][j]);
          acc[i][j] = fmaf(a[i].w, b[j].w, acc[i][j]);
        }
    }
    __syncthreads();
  }
  #pragma unroll
  for(int i=0;i<4;i++){
    int gr = rb + tr + 16*i;
    if (gr >= M) continue;
    #pragma unroll
    for(int j=0;j<4;j++)
      Cmat[(size_t)gr*J + cb + tc + 16*j] = acc[i][j];
  }
}

// ------------- rowwise after GEMM: matvec-nl -> proj -> mobius_add(hb) -> proj -> logmap0 -------------
template<int D>
__global__ void k_post_gemm(const float* __restrict__ mx, const float* __restrict__ nin,
                            const float* __restrict__ hb, float* __restrict__ xt, int N){
  constexpr int PL = D/64;
  int wid = (blockIdx.x*blockDim.x + threadIdx.x)>>6;
  int lane = threadIdx.x & 63;
  if (wid >= N) return;
  const float* row = mx + (size_t)wid*D;
  float m[PL], hv[PL];
  float ss=0.f, hb2=0.f;
  #pragma unroll
  for(int i=0;i<PL;i++){
    m[i] = row[lane+64*i];
    hv[i] = hb[lane+64*i];
    ss += m[i]*m[i];
    hb2 += hv[i]*hv[i];
  }
  ss = wred(ss);
  hb2 = wred(hb2);
  float mxn_raw = sqrtf(ss);
  float mxn = fmaxf(mxn_raw, 1e-15f);
  float xn = fmaxf(nin[wid], 1e-15f);
  float th = tanhf(mxn/xn * artanh_c(xn));
  float hs = (mxn_raw > 0.f) ? th/mxn : 0.f;
  float hn = (mxn_raw > 0.f) ? th : 0.f;
  if (hn > MAXN_P){ hs *= MAXN_P/hn; hn = MAXN_P; }
  float h[PL];
  float xy=0.f, x2=0.f;
  #pragma unroll
  for(int i=0;i<PL;i++){ h[i] = m[i]*hs; xy += h[i]*hv[i]; x2 += h[i]*h[i]; }
  xy = wred(xy); x2 = wred(x2);
  float c1 = 1.f + 2.f*xy + hb2;
  float c2 = 1.f - x2;
  float den = fmaxf(1.f + 2.f*xy + x2*hb2, 1e-15f);
  float a[PL]; float as=0.f;
  #pragma unroll
  for(int i=0;i<PL;i++){ a[i] = (c1*h[i] + c2*hv[i])/den; as += a[i]*a[i]; }
  as = wred(as);
  float an = fmaxf(sqrtf(as), 1e-15f);
  float s2 = 1.f;
  if (an > MAXN_P){ s2 = MAXN_P/an; an = MAXN_P; }
  float ls = artanh_c(an)/an * s2;
  #pragma unroll
  for(int i=0;i<PL;i++) xt[(size_t)wid*D + lane+64*i] = a[i]*ls;
}

// ---------------- spmm: st[i] = sum_{e: dst=i} w[e] * xt[src[e]] ----------------
template<int D>
__global__ void k_spmm(const int* __restrict__ rowptr, const int2* __restrict__ se,
                       const float* __restrict__ wv, const float* __restrict__ xt,
                       float* __restrict__ st, int N){
  constexpr int PL = D/64;
  int wid = (blockIdx.x*blockDim.x + threadIdx.x)>>6;
  int lane = threadIdx.x & 63;
  if (wid >= N) return;
  float acc[PL];
  #pragma unroll
  for(int i=0;i<PL;i++) acc[i] = 0.f;
  int p0 = rowptr[wid], p1 = rowptr[wid+1];
  for(int p=p0;p<p1;p++){
    int2 q = se[p];
    float w = wv[q.y];
    const float* r = xt + (size_t)q.x*D;
    #pragma unroll
    for(int i=0;i<PL;i++) acc[i] = fmaf(w, r[lane+64*i], acc[i]);
  }
  #pragma unroll
  for(int i=0;i<PL;i++) st[(size_t)wid*D + lane+64*i] = acc[i];
}

// ------- rowwise after spmm: proj(expmap0(st)) -> proj(expmap0(relu(logmap0(.)))) + norm out -------
template<int D>
__global__ void k_post_spmm(const float* __restrict__ st, float* __restrict__ hout,
                            float* __restrict__ nout, int N){
  constexpr int PL = D/64;
  int wid = (blockIdx.x*blockDim.x + threadIdx.x)>>6;
  int lane = threadIdx.x & 63;
  if (wid >= N) return;
  float u[PL]; float ss=0.f;
  #pragma unroll
  for(int i=0;i<PL;i++){ u[i] = st[(size_t)wid*D + lane+64*i]; ss += u[i]*u[i]; }
  ss = wred(ss);
  float un = fmaxf(sqrtf(ss), 1e-15f);
  float t1 = tanhf(un);
  float sc = t1/un;
  float pn = t1;
  if (pn > MAXN_P){ sc *= MAXN_P/pn; pn = MAXN_P; }
  float ln = fmaxf(pn, 1e-15f);
  float ls = artanh_c(ln)/ln;
  float v[PL]; float vs=0.f;
  #pragma unroll
  for(int i=0;i<PL;i++){ v[i] = fmaxf(u[i]*sc*ls, 0.f); vs += v[i]*v[i]; }
  vs = wred(vs);
  float vn = fmaxf(sqrtf(vs), 1e-15f);
  float t2 = tanhf(vn);
  float qs = t2/vn;
  float qn = t2;
  if (qn > MAXN_P){ qs *= MAXN_P/qn; qn = MAXN_P; }
  #pragma unroll
  for(int i=0;i<PL;i++) hout[(size_t)wid*D + lane+64*i] = v[i]*qs;
  if (lane == 0) nout[wid] = qn;
}

// ---------------- final combine (D=64, 1 float/lane) ----------------
__global__ void k_final(const float* __restrict__ bout, float* __restrict__ out,
                        int N, size_t bstride){
  int wid = (blockIdx.x*blockDim.x + threadIdx.x)>>6;
  int lane = threadIdx.x & 63;
  if (wid >= N) return;
  float xv[4], xn[4];
  #pragma unroll
  for(int k=0;k<4;k++){
    xv[k] = bout[k*bstride + (size_t)wid*64 + lane];
    xn[k] = fmaxf(sqrtf(wred(xv[k]*xv[k])), 1e-15f);
  }
  // t = mobius_mulscaler(0.125, x0)
  float tv = tanhf(0.125f*artanh_c(xn[0]))/xn[0] * xv[0];
  #pragma unroll
  for(int k=1;k<4;k++){
    float yv = tanhf(0.125f*artanh_c(xn[k]))/xn[k] * xv[k];
    float x2 = wred(tv*tv);
    float y2 = wred(yv*yv);
    float xy = wred(tv*yv);
    float c1 = 1.f + 2.f*xy + y2;
    float c2 = 1.f - x2;
    float den = fmaxf(1.f + 2.f*xy + x2*y2, 1e-15f);
    tv = (c1*tv + c2*yv)/den;
  }
  // agg = mean of logmap0 over {x0..x3, t}
  float s = 0.f;
  #pragma unroll
  for(int k=0;k<4;k++) s += artanh_c(xn[k])/xn[k] * xv[k];
  float tn = fmaxf(sqrtf(wred(tv*tv)), 1e-15f);
  s += artanh_c(tn)/tn * tv;
  s *= 0.2f;
  // out = proj(expmap0(agg))
  float an = fmaxf(sqrtf(wred(s*s)), 1e-15f);
  float on = tanhf(an);
  float osc = on/an;
  if (on > MAXN_P) osc *= MAXN_P/on;
  out[(size_t)wid*64 + lane] = s*osc;
}

extern "C" void kernel_launch(void* const* d_in, const int* in_sizes, int n_in,
                              void* d_out, int out_size, void* d_ws, size_t ws_size,
                              hipStream_t stream){
  const float* x   = (const float*)d_in[0];
  const int*   src = (const int*)d_in[1];
  const int*   dst = (const int*)d_in[2];
  const float* ew  = (const float*)d_in[3];   // [4,E]
  const float* W0  = (const float*)d_in[4];   // [4,HID,128]
  const float* b0  = (const float*)d_in[5];   // [4,HID]
  const float* W1  = (const float*)d_in[6];   // [4,DIM,HID]
  const float* b1  = (const float*)d_in[7];   // [4,DIM]
  float* out = (float*)d_out;

  const int FIN = 128;
  int N = in_sizes[0]/FIN;
  int E = in_sizes[1];
  int HID = in_sizes[5]/4;   // 128
  int DIM = in_sizes[7]/4;   // 64

  // workspace layout
  char* ws = (char*)d_ws;
  size_t off = 0;
  auto alloc = [&](size_t bytes)->char*{
    char* p = ws + off;
    off += (bytes + 255) & ~(size_t)255;
    return p;
  };
  float* h0     = (float*)alloc((size_t)N*FIN*4);
  float* n0     = (float*)alloc((size_t)N*4);
  float* n1     = (float*)alloc((size_t)N*4);
  float* bufA   = (float*)alloc((size_t)N*FIN*4);
  float* bufB   = (float*)alloc((size_t)N*FIN*4);
  float* bout   = (float*)alloc((size_t)4*N*DIM*4);
  int*   rowptr = (int*)alloc((size_t)(N+1)*4);
  int*   cnt    = (int*)alloc((size_t)N*4);
  int*   cursor = (int*)alloc((size_t)N*4);
  int2*  se     = (int2*)alloc((size_t)E*8);
  float* hb0    = (float*)alloc((size_t)4*HID*4);
  float* hb1    = (float*)alloc((size_t)4*DIM*4);
  (void)ws_size; (void)n_in; (void)out_size;

  int rowBlocks = (N + 3)/4;   // 4 waves (rows) per 256-thread block

  // CSR build (graph shared by all 8 spmms)
  hipMemsetAsync(cnt, 0, (size_t)N*4, stream);
  k_hist<<<(E+255)/256, 256, 0, stream>>>(dst, cnt, E);
  k_scan<<<1, 1024, 0, stream>>>(cnt, rowptr, cursor, N);
  k_fill<<<(E+255)/256, 256, 0, stream>>>(src, dst, cursor, se, E);

  // shared prologue
  k_exp0<<<rowBlocks, 256, 0, stream>>>(x, h0, n0, N);
  k_hb<<<8, 64, 0, stream>>>(b0, b1, hb0, hb1, HID, DIM);

  for(int br=0; br<4; br++){
    const float* w0b = W0 + (size_t)br*HID*FIN;
    const float* w1b = W1 + (size_t)br*DIM*HID;
    const float* wv  = ew + (size_t)br*E;
    // layer 0
    k_gemm<<<dim3((N+63)/64, HID/64), 256, 0, stream>>>(h0, w0b, bufA, N, HID);
    k_post_gemm<128><<<rowBlocks, 256, 0, stream>>>(bufA, n0, hb0 + (size_t)br*HID, bufA, N);
    k_spmm<128><<<rowBlocks, 256, 0, stream>>>(rowptr, se, wv, bufA, bufB, N);
    k_post_spmm<128><<<rowBlocks, 256, 0, stream>>>(bufB, bufB, n1, N);
    // layer 1
    k_gemm<<<dim3((N+63)/64, DIM/64), 256, 0, stream>>>(bufB, w1b, bufA, N, DIM);
    k_post_gemm<64><<<rowBlocks, 256, 0, stream>>>(bufA, n1, hb1 + (size_t)br*DIM, bufA, N);
    k_spmm<64><<<rowBlocks, 256, 0, stream>>>(rowptr, se, wv, bufA, bufB, N);
    k_post_spmm<64><<<rowBlocks, 256, 0, stream>>>(bufB, bout + (size_t)br*N*DIM, n1, N);
  }

  k_final<<<rowBlocks, 256, 0, stream>>>(bout, out, N, (size_t)N*DIM);
}

// Round 2
// 1392.895 us; speedup vs baseline: 1.6628x; 1.6628x over previous
//
#include <hip/hip_runtime.h>
#include <math.h>

#define MAXN_P 0.996f   // (1 - PROJ_EPS)/sqrt(c), c=1

__device__ __forceinline__ float wred(float v){
  #pragma unroll
  for(int o=32;o>0;o>>=1) v += __shfl_xor(v,o,64);
  return v;
}
template<int W>
__device__ __forceinline__ float gredw(float v){
  #pragma unroll
  for(int o=W/2;o>0;o>>=1) v += __shfl_xor(v,o,64);
  return v;
}
__device__ __forceinline__ float artanh_c(float x){
  x = fminf(fmaxf(x, -1.0f+1e-7f), 1.0f-1e-7f);
  return atanhf(x);
}
__device__ __forceinline__ float dot4(float4 a, float4 b){
  return a.x*b.x + a.y*b.y + a.z*b.z + a.w*b.w;
}
__device__ __forceinline__ void fma4(float4& a, float w, float4 v){
  a.x = fmaf(w, v.x, a.x); a.y = fmaf(w, v.y, a.y);
  a.z = fmaf(w, v.z, a.z); a.w = fmaf(w, v.w, a.w);
}
__device__ __forceinline__ float sel4(float4 w, int g){
  float ab = (g&1) ? w.y : w.x;
  float cd = (g&1) ? w.w : w.z;
  return (g&2) ? cd : ab;
}

// post_spmm chain on a float4 slice whose branch-norm lives across W lanes:
// u -> proj(expmap0(u)) -> relu(logmap0(.)) -> proj(expmap0(.)); returns h, qn=||h||
template<int W>
__device__ __forceinline__ float4 post_chain(float4 u, float& qn_out){
  float ss = gredw<W>(dot4(u,u));
  float un = fmaxf(sqrtf(ss), 1e-15f);
  float t1 = tanhf(un);
  float sc = t1/un;
  float pn = t1;
  if (pn > MAXN_P){ sc *= MAXN_P/pn; pn = MAXN_P; }
  float ln = fmaxf(pn, 1e-15f);
  float m = sc * (artanh_c(ln)/ln);
  float4 v;
  v.x = fmaxf(u.x*m, 0.f); v.y = fmaxf(u.y*m, 0.f);
  v.z = fmaxf(u.z*m, 0.f); v.w = fmaxf(u.w*m, 0.f);
  float vs = gredw<W>(dot4(v,v));
  float vn = fmaxf(sqrtf(vs), 1e-15f);
  float t2 = tanhf(vn);
  float qs = t2/vn;
  float qn = t2;
  if (qn > MAXN_P){ qs *= MAXN_P/qn; qn = MAXN_P; }
  qn_out = qn;
  return make_float4(v.x*qs, v.y*qs, v.z*qs, v.w*qs);
}

// ---------------- CSR build ----------------
__global__ void k_hist(const int* __restrict__ dst, int* __restrict__ cnt, int E){
  int e = blockIdx.x*blockDim.x + threadIdx.x;
  if (e < E) atomicAdd(&cnt[dst[e]], 1);
}

__global__ void k_scan(const int* __restrict__ cnt, int* __restrict__ rowptr,
                       int* __restrict__ cursor, int N){
  __shared__ int sh[1024];
  int t = threadIdx.x;
  int chunk = (N + 1023) / 1024;
  int b = t*chunk;
  int e = b + chunk; if (e > N) e = N;
  int s = 0;
  for(int i=b;i<e && i<N;i++) s += cnt[i];
  sh[t] = s;
  __syncthreads();
  for(int off=1; off<1024; off<<=1){
    int add = (t>=off) ? sh[t-off] : 0;
    __syncthreads();
    sh[t] += add;
    __syncthreads();
  }
  int run = (t==0) ? 0 : sh[t-1];
  for(int i=b;i<e && i<N;i++){
    rowptr[i] = run; cursor[i] = run; run += cnt[i];
  }
  if (t == 1023) rowptr[N] = run;
}

// fill CSR: src index + 4 branch weights interleaved IN CSR ORDER (sequential in spmm)
__global__ void k_fill(const int* __restrict__ src, const int* __restrict__ dst,
                       const float* __restrict__ ew, int E,
                       int* __restrict__ cursor, int* __restrict__ srcs,
                       float4* __restrict__ wq){
  int e = blockIdx.x*blockDim.x + threadIdx.x;
  if (e >= E) return;
  int d = dst[e];
  int pos = atomicAdd(&cursor[d], 1);
  srcs[pos] = src[e];
  wq[pos] = make_float4(ew[e], ew[(size_t)E + e], ew[2*(size_t)E + e], ew[3*(size_t)E + e]);
}

// ---------------- rowwise: h0 = proj(expmap0(x)), n0 = ||h0|| ----------------
__global__ void k_exp0(const float* __restrict__ x, float* __restrict__ h0,
                       float* __restrict__ n0, int N){
  int wid = (blockIdx.x*blockDim.x + threadIdx.x)>>6;
  int lane = threadIdx.x & 63;
  if (wid >= N) return;
  const float* r = x + (size_t)wid*128;
  float u0 = r[lane], u1 = r[lane+64];
  float ss = wred(u0*u0 + u1*u1);
  float un = fmaxf(sqrtf(ss), 1e-15f);
  float tn = tanhf(un);
  float sc = tn/un;
  float pn = tn;
  if (pn > MAXN_P){ sc *= MAXN_P/pn; pn = MAXN_P; }
  h0[(size_t)wid*128 + lane]      = u0*sc;
  h0[(size_t)wid*128 + lane + 64] = u1*sc;
  if (lane == 0) n0[wid] = pn;
}

// ---------------- hb = proj(expmap0(b)) for 4 branches x 2 layers ----------------
__global__ void k_hb(const float* __restrict__ b0, const float* __restrict__ b1,
                     float* __restrict__ hb0, float* __restrict__ hb1,
                     int HID, int DIM){
  int bl = blockIdx.x;       // 0..7
  int lane = threadIdx.x;    // 64
  int layer = bl >> 2, br = bl & 3;
  int D = layer ? DIM : HID;
  const float* b = layer ? (b1 + (size_t)br*DIM) : (b0 + (size_t)br*HID);
  float* o       = layer ? (hb1 + (size_t)br*DIM) : (hb0 + (size_t)br*HID);
  float v0 = (lane < D) ? b[lane] : 0.f;
  float v1 = (lane+64 < D) ? b[lane+64] : 0.f;
  float ss = wred(v0*v0 + v1*v1);
  float n = fmaxf(sqrtf(ss), 1e-15f);
  float tn = tanhf(n);
  float sc = tn/n;
  if (tn > MAXN_P) sc *= MAXN_P/tn;
  if (lane < D)    o[lane]    = v0*sc;
  if (lane+64 < D) o[lane+64] = v1*sc;
}

// ---------------- batched f32 GEMM: C[br][M,J] = A[br][M,128] * W[br][J,128]^T ----------------
__global__ __launch_bounds__(256) void k_gemm(const float* __restrict__ Abase, int lda, int abroff,
                                              const float* __restrict__ Wbase,
                                              float* __restrict__ Cbase, int ldc,
                                              int M, int J){
  __shared__ float Al[64*68];
  __shared__ float Wl[64*68];
  int br = blockIdx.z;
  const float* A = Abase + (size_t)br*abroff;
  const float* W = Wbase + (size_t)br*J*128;
  float* Cmat = Cbase + (size_t)br*J;
  int rb = blockIdx.x*64;
  int cb = blockIdx.y*64;
  int t = threadIdx.x;
  int tr = t >> 4, tc = t & 15;
  float acc[4][4] = {};
  for(int kk=0; kk<128; kk+=64){
    #pragma unroll
    for(int i=0;i<4;i++){
      int idx = t + i*256;
      int r = idx>>4, k4 = idx&15;
      float4 v = make_float4(0,0,0,0);
      int gr = rb + r;
      if (gr < M) v = *(const float4*)(A + (size_t)gr*lda + kk + k4*4);
      *(float4*)(Al + r*68 + k4*4) = v;
    }
    #pragma unroll
    for(int i=0;i<4;i++){
      int idx = t + i*256;
      int r = idx>>4, k4 = idx&15;
      float4 v = *(const float4*)(W + (size_t)(cb + r)*128 + kk + k4*4);
      *(float4*)(Wl + r*68 + k4*4) = v;
    }
    __syncthreads();
    #pragma unroll
    for(int k=0;k<64;k+=4){
      float4 a[4], b[4];
      #pragma unroll
      for(int i=0;i<4;i++) a[i] = *(float4*)(Al + (tr+16*i)*68 + k);
      #pragma unroll
      for(int i=0;i<4;i++) b[i] = *(float4*)(Wl + (tc+16*i)*68 + k);
      #pragma unroll
      for(int i=0;i<4;i++)
        #pragma unroll
        for(int j=0;j<4;j++){
          acc[i][j] = fmaf(a[i].x, b[j].x, acc[i][j]);
          acc[i][j] = fmaf(a[i].y, b[j].y, acc[i][j]);
          acc[i][j] = fmaf(a[i].z, b[j].z, acc[i][j]);
          acc[i][j] = fmaf(a[i].w, b[j].w, acc[i][j]);
        }
    }
    __syncthreads();
  }
  #pragma unroll
  for(int i=0;i<4;i++){
    int gr = rb + tr + 16*i;
    if (gr >= M) continue;
    #pragma unroll
    for(int j=0;j<4;j++)
      Cmat[(size_t)gr*ldc + cb + tc + 16*j] = acc[i][j];
  }
}

// ------------- rowwise after GEMM (all 4 branches, wave per (node,branch)) -------------
// matvec-nl -> proj -> mobius_add(hb) -> proj -> logmap0 ; in-place on buf[N][4][D]
template<int D>
__global__ void k_post_gemm4(float* __restrict__ buf, const float* __restrict__ nin,
                             int nstride, int nbroff,
                             const float* __restrict__ hball, int N){
  constexpr int PL = D/64;
  int gid = (blockIdx.x*blockDim.x + threadIdx.x)>>6;
  int lane = threadIdx.x & 63;
  if (gid >= 4*N) return;
  int node = gid>>2, br = gid&3;
  float* row = buf + (size_t)node*(4*D) + (size_t)br*D;
  const float* hb = hball + (size_t)br*D;
  float m[PL], hv[PL];
  float ss=0.f, hb2=0.f;
  #pragma unroll
  for(int i=0;i<PL;i++){
    m[i] = row[lane+64*i];
    hv[i] = hb[lane+64*i];
    ss += m[i]*m[i];
    hb2 += hv[i]*hv[i];
  }
  ss = wred(ss);
  hb2 = wred(hb2);
  float mxn_raw = sqrtf(ss);
  float mxn = fmaxf(mxn_raw, 1e-15f);
  float xn = fmaxf(nin[(size_t)node*nstride + br*nbroff], 1e-15f);
  float th = tanhf(mxn/xn * artanh_c(xn));
  float hs = (mxn_raw > 0.f) ? th/mxn : 0.f;
  float hn = (mxn_raw > 0.f) ? th : 0.f;
  if (hn > MAXN_P){ hs *= MAXN_P/hn; hn = MAXN_P; }
  float h[PL];
  float xy=0.f, x2=0.f;
  #pragma unroll
  for(int i=0;i<PL;i++){ h[i] = m[i]*hs; xy += h[i]*hv[i]; x2 += h[i]*h[i]; }
  xy = wred(xy); x2 = wred(x2);
  float c1 = 1.f + 2.f*xy + hb2;
  float c2 = 1.f - x2;
  float den = fmaxf(1.f + 2.f*xy + x2*hb2, 1e-15f);
  float a[PL]; float as=0.f;
  #pragma unroll
  for(int i=0;i<PL;i++){ a[i] = (c1*h[i] + c2*hv[i])/den; as += a[i]*a[i]; }
  as = wred(as);
  float an = fmaxf(sqrtf(as), 1e-15f);
  float s2 = 1.f;
  if (an > MAXN_P){ s2 = MAXN_P/an; an = MAXN_P; }
  float ls = artanh_c(an)/an * s2;
  #pragma unroll
  for(int i=0;i<PL;i++) row[lane+64*i] = a[i]*ls;
}

// -------- fused 4-branch spmm layer0 (D=128, 2KB/row) + post_spmm epilogue --------
// xt: [N][4][128] in bufX ; writes h4 to bufY [N][4][128] and n4[N][4]
__global__ __launch_bounds__(256) void k_spmm_l0(const int* __restrict__ rowptr,
                        const int* __restrict__ srcs, const float4* __restrict__ wq,
                        const float* __restrict__ xt,
                        float* __restrict__ hout, float* __restrict__ n4, int N){
  int wid = (blockIdx.x*blockDim.x + threadIdx.x)>>6;
  int lane = threadIdx.x & 63;
  if (wid >= N) return;
  int g = lane>>5;               // 0/1 : acc0 holds branch g, acc1 holds branch 2+g
  int o0 = 4*lane;
  int o1 = 256 + 4*lane;
  float4 acc0 = {0,0,0,0}, acc1 = {0,0,0,0};
  int p0 = rowptr[wid], p1 = rowptr[wid+1];
  int p = p0;
  for (; p+1 < p1; p += 2){
    int s0 = srcs[p], s1 = srcs[p+1];
    float4 w0 = wq[p], w1 = wq[p+1];
    const float* r0 = xt + (size_t)s0*512;
    const float* r1 = xt + (size_t)s1*512;
    float4 a00 = *(const float4*)(r0 + o0);
    float4 a01 = *(const float4*)(r0 + o1);
    float4 a10 = *(const float4*)(r1 + o0);
    float4 a11 = *(const float4*)(r1 + o1);
    float wa0 = g ? w0.y : w0.x;  float wb0 = g ? w0.w : w0.z;
    float wa1 = g ? w1.y : w1.x;  float wb1 = g ? w1.w : w1.z;
    fma4(acc0, wa0, a00); fma4(acc1, wb0, a01);
    fma4(acc0, wa1, a10); fma4(acc1, wb1, a11);
  }
  if (p < p1){
    int s0 = srcs[p];
    float4 w0 = wq[p];
    const float* r0 = xt + (size_t)s0*512;
    float wa0 = g ? w0.y : w0.x;  float wb0 = g ? w0.w : w0.z;
    fma4(acc0, wa0, *(const float4*)(r0 + o0));
    fma4(acc1, wb0, *(const float4*)(r0 + o1));
  }
  // fused post_spmm per branch slice (norms live across 32-lane groups)
  float qn0, qn1;
  float4 h0v = post_chain<32>(acc0, qn0);
  float4 h1v = post_chain<32>(acc1, qn1);
  float* orow = hout + (size_t)wid*512;
  *(float4*)(orow + o0) = h0v;
  *(float4*)(orow + o1) = h1v;
  if ((lane&31)==0){
    n4[(size_t)wid*4 + g]     = qn0;
    n4[(size_t)wid*4 + 2 + g] = qn1;
  }
}

// -------- fused 4-branch spmm layer1 (D=64, 1KB/row) + post_spmm + Mobius combine --------
// xt: [N][4][64] in bufX ; writes final output [N][64]
__global__ __launch_bounds__(256) void k_spmm_l1(const int* __restrict__ rowptr,
                        const int* __restrict__ srcs, const float4* __restrict__ wq,
                        const float* __restrict__ xt,
                        float* __restrict__ out, int N){
  int wid = (blockIdx.x*blockDim.x + threadIdx.x)>>6;
  int lane = threadIdx.x & 63;
  if (wid >= N) return;
  int g = lane>>4;               // branch 0..3 (16-lane groups)
  int slot = lane & 15;
  int o = 4*lane;
  float4 acc = {0,0,0,0};
  int p0 = rowptr[wid], p1 = rowptr[wid+1];
  int p = p0;
  for (; p+1 < p1; p += 2){
    int s0 = srcs[p], s1 = srcs[p+1];
    float4 w0 = wq[p], w1 = wq[p+1];
    float4 a0 = *(const float4*)(xt + (size_t)s0*256 + o);
    float4 a1 = *(const float4*)(xt + (size_t)s1*256 + o);
    fma4(acc, sel4(w0,g), a0);
    fma4(acc, sel4(w1,g), a1);
  }
  if (p < p1){
    int s0 = srcs[p];
    float4 w0 = wq[p];
    fma4(acc, sel4(w0,g), *(const float4*)(xt + (size_t)s0*256 + o));
  }
  // per-branch post_spmm chain (norms across 16-lane groups)
  float qn;
  float4 h = post_chain<16>(acc, qn);
  // cross-branch gather: every lane collects all 4 branches' values for its dim slot
  float4 xk[4]; float qk[4];
  #pragma unroll
  for(int k=0;k<4;k++){
    xk[k].x = __shfl(h.x, slot + 16*k, 64);
    xk[k].y = __shfl(h.y, slot + 16*k, 64);
    xk[k].z = __shfl(h.z, slot + 16*k, 64);
    xk[k].w = __shfl(h.w, slot + 16*k, 64);
    qk[k]   = __shfl(qn,  16*k, 64);
  }
  // target = chain of mobius_add(mobius_mulscaler(0.125, x_k))
  float xn0 = fmaxf(qk[0], 1e-15f);
  float s0 = tanhf(0.125f*artanh_c(xn0))/xn0;
  float4 t = make_float4(s0*xk[0].x, s0*xk[0].y, s0*xk[0].z, s0*xk[0].w);
  #pragma unroll
  for(int k=1;k<4;k++){
    float yn = fmaxf(qk[k], 1e-15f);
    float sy = tanhf(0.125f*artanh_c(yn))/yn;
    float4 y = make_float4(sy*xk[k].x, sy*xk[k].y, sy*xk[k].z, sy*xk[k].w);
    float x2 = gredw<16>(dot4(t,t));
    float y2 = gredw<16>(dot4(y,y));
    float xy = gredw<16>(dot4(t,y));
    float c1 = 1.f + 2.f*xy + y2;
    float c2 = 1.f - x2;
    float den = fmaxf(1.f + 2.f*xy + x2*y2, 1e-15f);
    t.x = (c1*t.x + c2*y.x)/den;
    t.y = (c1*t.y + c2*y.y)/den;
    t.z = (c1*t.z + c2*y.z)/den;
    t.w = (c1*t.w + c2*y.w)/den;
  }
  // agg = mean of logmap0 over {x0..x3, t}
  float4 s = {0,0,0,0};
  #pragma unroll
  for(int k=0;k<4;k++){
    float nk = fmaxf(qk[k], 1e-15f);
    float lk = artanh_c(nk)/nk;
    fma4(s, lk, xk[k]);
  }
  float tn = fmaxf(sqrtf(gredw<16>(dot4(t,t))), 1e-15f);
  fma4(s, artanh_c(tn)/tn, t);
  s.x *= 0.2f; s.y *= 0.2f; s.z *= 0.2f; s.w *= 0.2f;
  // out = proj(expmap0(agg))
  float an = fmaxf(sqrtf(gredw<16>(dot4(s,s))), 1e-15f);
  float on = tanhf(an);
  float osc = on/an;
  if (on > MAXN_P) osc *= MAXN_P/on;
  if (g == 0)
    *(float4*)(out + (size_t)wid*64 + 4*slot) =
      make_float4(s.x*osc, s.y*osc, s.z*osc, s.w*osc);
}

extern "C" void kernel_launch(void* const* d_in, const int* in_sizes, int n_in,
                              void* d_out, int out_size, void* d_ws, size_t ws_size,
                              hipStream_t stream){
  const float* x   = (const float*)d_in[0];
  const int*   src = (const int*)d_in[1];
  const int*   dst = (const int*)d_in[2];
  const float* ew  = (const float*)d_in[3];   // [4,E]
  const float* W0  = (const float*)d_in[4];   // [4,HID,128]
  const float* b0  = (const float*)d_in[5];   // [4,HID]
  const float* W1  = (const float*)d_in[6];   // [4,DIM,HID]
  const float* b1  = (const float*)d_in[7];   // [4,DIM]
  float* out = (float*)d_out;

  const int FIN = 128;
  int N = in_sizes[0]/FIN;
  int E = in_sizes[1];
  int HID = in_sizes[5]/4;   // 128
  int DIM = in_sizes[7]/4;   // 64

  char* ws = (char*)d_ws;
  size_t off = 0;
  auto alloc = [&](size_t bytes)->char*{
    char* p = ws + off;
    off += (bytes + 255) & ~(size_t)255;
    return p;
  };
  float* bufX   = (float*)alloc((size_t)N*4*FIN*4);  // 102.4 MB: mx4 / xt4 / mx4b / xt4b
  float* bufY   = (float*)alloc((size_t)N*4*FIN*4);  // 102.4 MB: h0 (prefix) / h4
  float* n0     = (float*)alloc((size_t)N*4);
  float* n4     = (float*)alloc((size_t)N*16);
  int*   rowptr = (int*)alloc((size_t)(N+1)*4);
  int*   cnt    = (int*)alloc((size_t)N*4);
  int*   cursor = (int*)alloc((size_t)N*4);
  int*   srcs   = (int*)alloc((size_t)E*4);
  float4* wq    = (float4*)alloc((size_t)E*16);
  float* hb0    = (float*)alloc((size_t)4*HID*4);
  float* hb1    = (float*)alloc((size_t)4*DIM*4);
  (void)ws_size; (void)n_in; (void)out_size;

  float* h0 = bufY;            // [N,128] alias; dead before spmm_l0 writes bufY
  int rowBlocks  = (N + 3)/4;      // wave per node
  int rowBlocks4 = N;              // wave per (node,branch): 4N waves / 4 per block

  // CSR build (shared by both fused spmms); weights packed in CSR order
  hipMemsetAsync(cnt, 0, (size_t)N*4, stream);
  k_hist<<<(E+255)/256, 256, 0, stream>>>(dst, cnt, E);
  k_scan<<<1, 1024, 0, stream>>>(cnt, rowptr, cursor, N);
  k_fill<<<(E+255)/256, 256, 0, stream>>>(src, dst, ew, E, cursor, srcs, wq);

  // prologue
  k_exp0<<<rowBlocks, 256, 0, stream>>>(x, h0, n0, N);
  k_hb<<<8, 64, 0, stream>>>(b0, b1, hb0, hb1, HID, DIM);

  // layer 0: batched GEMM -> fused rowwise -> fused spmm(+post)
  k_gemm<<<dim3((N+63)/64, HID/64, 4), 256, 0, stream>>>(h0, FIN, 0, W0, bufX, 4*HID, N, HID);
  k_post_gemm4<128><<<rowBlocks4, 256, 0, stream>>>(bufX, n0, 1, 0, hb0, N);
  k_spmm_l0<<<rowBlocks, 256, 0, stream>>>(rowptr, srcs, wq, bufX, bufY, n4, N);

  // layer 1: batched GEMM -> fused rowwise -> fused spmm(+post+combine) -> out
  k_gemm<<<dim3((N+63)/64, DIM/64, 4), 256, 0, stream>>>(bufY, 4*HID, HID, W1, bufX, 4*DIM, N, DIM);
  k_post_gemm4<64><<<rowBlocks4, 256, 0, stream>>>(bufX, n4, 4, 1, hb1, N);
  k_spmm_l1<<<rowBlocks, 256, 0, stream>>>(rowptr, srcs, wq, bufX, out, N);
}

// Round 3
// 1064.202 us; speedup vs baseline: 2.1763x; 1.3089x over previous
//
#include <hip/hip_runtime.h>
#include <math.h>

#define MAXN_P 0.996f   // (1 - PROJ_EPS)/sqrt(c), c=1

typedef unsigned short bfraw;

__device__ __forceinline__ float wred(float v){
  #pragma unroll
  for(int o=32;o>0;o>>=1) v += __shfl_xor(v,o,64);
  return v;
}
template<int W>
__device__ __forceinline__ float gredw(float v){
  #pragma unroll
  for(int o=W/2;o>0;o>>=1) v += __shfl_xor(v,o,64);
  return v;
}
__device__ __forceinline__ float artanh_c(float x){
  x = fminf(fmaxf(x, -1.0f+1e-7f), 1.0f-1e-7f);
  return atanhf(x);
}
__device__ __forceinline__ float sel4(float4 w, int g){
  float ab = (g&1) ? w.y : w.x;
  float cd = (g&1) ? w.w : w.z;
  return (g&2) ? cd : ab;
}
__device__ __forceinline__ bfraw f2bf(float f){
  unsigned u = __float_as_uint(f);
  unsigned r = (u + 0x7fffu + ((u>>16)&1u)) >> 16;   // RNE
  return (bfraw)r;
}
__device__ __forceinline__ float bflo(unsigned u){ return __uint_as_float(u<<16); }
__device__ __forceinline__ float bfhi(unsigned u){ return __uint_as_float(u & 0xffff0000u); }

// accumulate 8 bf16 (uint4) with weight w into acc[8]
__device__ __forceinline__ void acc8(float* a, float w, uint4 u){
  a[0]=fmaf(w, bflo(u.x), a[0]); a[1]=fmaf(w, bfhi(u.x), a[1]);
  a[2]=fmaf(w, bflo(u.y), a[2]); a[3]=fmaf(w, bfhi(u.y), a[3]);
  a[4]=fmaf(w, bflo(u.z), a[4]); a[5]=fmaf(w, bfhi(u.z), a[5]);
  a[6]=fmaf(w, bflo(u.w), a[6]); a[7]=fmaf(w, bfhi(u.w), a[7]);
}
__device__ __forceinline__ void acc4(float* a, float w, uint2 u){
  a[0]=fmaf(w, bflo(u.x), a[0]); a[1]=fmaf(w, bfhi(u.x), a[1]);
  a[2]=fmaf(w, bflo(u.y), a[2]); a[3]=fmaf(w, bfhi(u.y), a[3]);
}

// post_spmm chain: u -> proj(expmap0(u)) -> relu(logmap0) -> proj(expmap0); norms over W lanes
template<int W, int K>
__device__ __forceinline__ float postK(const float* u, float* h){
  float ss = 0.f;
  #pragma unroll
  for(int k=0;k<K;k++) ss += u[k]*u[k];
  ss = gredw<W>(ss);
  float un = fmaxf(sqrtf(ss), 1e-15f);
  float t1 = tanhf(un);
  float sc = t1/un;
  float pn = t1;
  if (pn > MAXN_P){ sc *= MAXN_P/pn; pn = MAXN_P; }
  float ln = fmaxf(pn, 1e-15f);
  float m = sc * (artanh_c(ln)/ln);
  float v[K]; float vs = 0.f;
  #pragma unroll
  for(int k=0;k<K;k++){ v[k] = fmaxf(u[k]*m, 0.f); vs += v[k]*v[k]; }
  vs = gredw<W>(vs);
  float vn = fmaxf(sqrtf(vs), 1e-15f);
  float t2 = tanhf(vn);
  float qs = t2/vn;
  float qn = t2;
  if (qn > MAXN_P){ qs *= MAXN_P/qn; qn = MAXN_P; }
  #pragma unroll
  for(int k=0;k<K;k++) h[k] = v[k]*qs;
  return qn;
}

// ---------------- CSR build ----------------
__global__ void k_hist(const int* __restrict__ dst, int* __restrict__ cnt, int E){
  int e = blockIdx.x*blockDim.x + threadIdx.x;
  if (e < E) atomicAdd(&cnt[dst[e]], 1);
}

__global__ void k_scan(const int* __restrict__ cnt, int* __restrict__ rowptr,
                       int* __restrict__ cursor, int N){
  __shared__ int sh[1024];
  int t = threadIdx.x;
  int chunk = (N + 1023) / 1024;
  int b = t*chunk;
  int e = b + chunk; if (e > N) e = N;
  int s = 0;
  for(int i=b;i<e && i<N;i++) s += cnt[i];
  sh[t] = s;
  __syncthreads();
  for(int off=1; off<1024; off<<=1){
    int add = (t>=off) ? sh[t-off] : 0;
    __syncthreads();
    sh[t] += add;
    __syncthreads();
  }
  int run = (t==0) ? 0 : sh[t-1];
  for(int i=b;i<e && i<N;i++){
    rowptr[i] = run; cursor[i] = run; run += cnt[i];
  }
  if (t == 1023) rowptr[N] = run;
}

__global__ void k_fill(const int* __restrict__ src, const int* __restrict__ dst,
                       const float* __restrict__ ew, int E,
                       int* __restrict__ cursor, int* __restrict__ srcs,
                       float4* __restrict__ wq){
  int e = blockIdx.x*blockDim.x + threadIdx.x;
  if (e >= E) return;
  int d = dst[e];
  int pos = atomicAdd(&cursor[d], 1);
  srcs[pos] = src[e];
  wq[pos] = make_float4(ew[e], ew[(size_t)E + e], ew[2*(size_t)E + e], ew[3*(size_t)E + e]);
}

// ---------------- rowwise: h0 = proj(expmap0(x)), n0 = ||h0|| ----------------
__global__ void k_exp0(const float* __restrict__ x, float* __restrict__ h0,
                       float* __restrict__ n0, int N){
  int wid = (blockIdx.x*blockDim.x + threadIdx.x)>>6;
  int lane = threadIdx.x & 63;
  if (wid >= N) return;
  const float* r = x + (size_t)wid*128;
  float u0 = r[lane], u1 = r[lane+64];
  float ss = wred(u0*u0 + u1*u1);
  float un = fmaxf(sqrtf(ss), 1e-15f);
  float tn = tanhf(un);
  float sc = tn/un;
  float pn = tn;
  if (pn > MAXN_P){ sc *= MAXN_P/pn; pn = MAXN_P; }
  h0[(size_t)wid*128 + lane]      = u0*sc;
  h0[(size_t)wid*128 + lane + 64] = u1*sc;
  if (lane == 0) n0[wid] = pn;
}

// ---------------- hb = proj(expmap0(b)) for 4 branches x 2 layers ----------------
__global__ void k_hb(const float* __restrict__ b0, const float* __restrict__ b1,
                     float* __restrict__ hb0, float* __restrict__ hb1,
                     int HID, int DIM){
  int bl = blockIdx.x;       // 0..7
  int lane = threadIdx.x;    // 64
  int layer = bl >> 2, br = bl & 3;
  int D = layer ? DIM : HID;
  const float* b = layer ? (b1 + (size_t)br*DIM) : (b0 + (size_t)br*HID);
  float* o       = layer ? (hb1 + (size_t)br*DIM) : (hb0 + (size_t)br*HID);
  float v0 = (lane < D) ? b[lane] : 0.f;
  float v1 = (lane+64 < D) ? b[lane+64] : 0.f;
  float ss = wred(v0*v0 + v1*v1);
  float n = fmaxf(sqrtf(ss), 1e-15f);
  float tn = tanhf(n);
  float sc = tn/n;
  if (tn > MAXN_P) sc *= MAXN_P/tn;
  if (lane < D)    o[lane]    = v0*sc;
  if (lane+64 < D) o[lane+64] = v1*sc;
}

// ---------------- batched GEMM: C[br][M,J] = A[br][M,128] * W[br][J,128]^T ----------------
__device__ __forceinline__ float4 ld4(const float* p){ return *(const float4*)p; }
__device__ __forceinline__ float4 ld4(const bfraw* p){
  uint2 u = *(const uint2*)p;
  return make_float4(bflo(u.x), bfhi(u.x), bflo(u.y), bfhi(u.y));
}

template<typename AT>
__global__ __launch_bounds__(256) void k_gemm(const AT* __restrict__ Abase, int lda, int abroff,
                                              const float* __restrict__ Wbase,
                                              float* __restrict__ Cbase, int ldc,
                                              int M, int J){
  __shared__ float Al[64*68];
  __shared__ float Wl[64*68];
  int br = blockIdx.z;
  const AT* A = Abase + (size_t)br*abroff;
  const float* W = Wbase + (size_t)br*J*128;
  float* Cmat = Cbase + (size_t)br*J;
  int rb = blockIdx.x*64;
  int cb = blockIdx.y*64;
  int t = threadIdx.x;
  int tr = t >> 4, tc = t & 15;
  float acc[4][4] = {};
  for(int kk=0; kk<128; kk+=64){
    #pragma unroll
    for(int i=0;i<4;i++){
      int idx = t + i*256;
      int r = idx>>4, k4 = idx&15;
      float4 v = make_float4(0,0,0,0);
      int gr = rb + r;
      if (gr < M) v = ld4(A + (size_t)gr*lda + kk + k4*4);
      *(float4*)(Al + r*68 + k4*4) = v;
    }
    #pragma unroll
    for(int i=0;i<4;i++){
      int idx = t + i*256;
      int r = idx>>4, k4 = idx&15;
      float4 v = *(const float4*)(W + (size_t)(cb + r)*128 + kk + k4*4);
      *(float4*)(Wl + r*68 + k4*4) = v;
    }
    __syncthreads();
    #pragma unroll
    for(int k=0;k<64;k+=4){
      float4 a[4], b[4];
      #pragma unroll
      for(int i=0;i<4;i++) a[i] = *(float4*)(Al + (tr+16*i)*68 + k);
      #pragma unroll
      for(int i=0;i<4;i++) b[i] = *(float4*)(Wl + (tc+16*i)*68 + k);
      #pragma unroll
      for(int i=0;i<4;i++)
        #pragma unroll
        for(int j=0;j<4;j++){
          acc[i][j] = fmaf(a[i].x, b[j].x, acc[i][j]);
          acc[i][j] = fmaf(a[i].y, b[j].y, acc[i][j]);
          acc[i][j] = fmaf(a[i].z, b[j].z, acc[i][j]);
          acc[i][j] = fmaf(a[i].w, b[j].w, acc[i][j]);
        }
    }
    __syncthreads();
  }
  #pragma unroll
  for(int i=0;i<4;i++){
    int gr = rb + tr + 16*i;
    if (gr >= M) continue;
    #pragma unroll
    for(int j=0;j<4;j++)
      Cmat[(size_t)gr*ldc + cb + tc + 16*j] = acc[i][j];
  }
}

// ------------- rowwise after GEMM: matvec-nl -> proj -> mobius_add(hb) -> proj -> logmap0 -------------
// reads f32 mx4[N][4][D], writes bf16 xt[N][4][D]
template<int D>
__global__ void k_post_gemm4(const float* __restrict__ mx4, bfraw* __restrict__ xt,
                             const float* __restrict__ nin, int nstride, int nbroff,
                             const float* __restrict__ hball, int N){
  constexpr int PL = D/64;
  int gid = (blockIdx.x*blockDim.x + threadIdx.x)>>6;
  int lane = threadIdx.x & 63;
  if (gid >= 4*N) return;
  int node = gid>>2, br = gid&3;
  const float* row = mx4 + (size_t)node*(4*D) + (size_t)br*D;
  bfraw* orow = xt + (size_t)node*(4*D) + (size_t)br*D;
  const float* hb = hball + (size_t)br*D;
  float m[PL], hv[PL];
  float ss=0.f, hb2=0.f;
  #pragma unroll
  for(int i=0;i<PL;i++){
    m[i] = row[lane+64*i];
    hv[i] = hb[lane+64*i];
    ss += m[i]*m[i];
    hb2 += hv[i]*hv[i];
  }
  ss = wred(ss);
  hb2 = wred(hb2);
  float mxn_raw = sqrtf(ss);
  float mxn = fmaxf(mxn_raw, 1e-15f);
  float xn = fmaxf(nin[(size_t)node*nstride + br*nbroff], 1e-15f);
  float th = tanhf(mxn/xn * artanh_c(xn));
  float hs = (mxn_raw > 0.f) ? th/mxn : 0.f;
  float hn = (mxn_raw > 0.f) ? th : 0.f;
  if (hn > MAXN_P){ hs *= MAXN_P/hn; hn = MAXN_P; }
  float h[PL];
  float xy=0.f, x2=0.f;
  #pragma unroll
  for(int i=0;i<PL;i++){ h[i] = m[i]*hs; xy += h[i]*hv[i]; x2 += h[i]*h[i]; }
  xy = wred(xy); x2 = wred(x2);
  float c1 = 1.f + 2.f*xy + hb2;
  float c2 = 1.f - x2;
  float den = fmaxf(1.f + 2.f*xy + x2*hb2, 1e-15f);
  float a[PL]; float as=0.f;
  #pragma unroll
  for(int i=0;i<PL;i++){ a[i] = (c1*h[i] + c2*hv[i])/den; as += a[i]*a[i]; }
  as = wred(as);
  float an = fmaxf(sqrtf(as), 1e-15f);
  float s2 = 1.f;
  if (an > MAXN_P){ s2 = MAXN_P/an; an = MAXN_P; }
  float ls = artanh_c(an)/an * s2;
  #pragma unroll
  for(int i=0;i<PL;i++) orow[lane+64*i] = f2bf(a[i]*ls);
}

// -------- fused 4-branch spmm layer0 (bf16 table, 1KB/row) + post_spmm epilogue --------
// xt: bf16 [N][4][128]; writes h4 bf16 [N][4][128] (layer-1 GEMM A) and n4[N][4]
__global__ __launch_bounds__(256) void k_spmm_l0(const int* __restrict__ rowptr,
                        const int* __restrict__ srcs, const float4* __restrict__ wq,
                        const bfraw* __restrict__ xt,
                        bfraw* __restrict__ hout, float* __restrict__ n4, int N){
  int wid = (blockIdx.x*blockDim.x + threadIdx.x)>>6;
  int lane = threadIdx.x & 63;
  if (wid >= N) return;
  int g = lane>>4;               // branch (16-lane groups, 8 dims/lane)
  float acc[8] = {0,0,0,0,0,0,0,0};
  int p0 = rowptr[wid], p1 = rowptr[wid+1];
  int p = p0;
  for (; p+4 <= p1; p += 4){
    int s0 = srcs[p], s1 = srcs[p+1], s2 = srcs[p+2], s3 = srcs[p+3];
    float4 w0 = wq[p], w1 = wq[p+1], w2 = wq[p+2], w3 = wq[p+3];
    uint4 u0 = *((const uint4*)(xt + (size_t)s0*512) + lane);
    uint4 u1 = *((const uint4*)(xt + (size_t)s1*512) + lane);
    uint4 u2 = *((const uint4*)(xt + (size_t)s2*512) + lane);
    uint4 u3 = *((const uint4*)(xt + (size_t)s3*512) + lane);
    acc8(acc, sel4(w0,g), u0);
    acc8(acc, sel4(w1,g), u1);
    acc8(acc, sel4(w2,g), u2);
    acc8(acc, sel4(w3,g), u3);
  }
  for (; p < p1; ++p){
    int s0 = srcs[p];
    float4 w0 = wq[p];
    uint4 u0 = *((const uint4*)(xt + (size_t)s0*512) + lane);
    acc8(acc, sel4(w0,g), u0);
  }
  float h[8];
  float qn = postK<16,8>(acc, h);
  uint4 o;
  o.x = (unsigned)f2bf(h[0]) | ((unsigned)f2bf(h[1])<<16);
  o.y = (unsigned)f2bf(h[2]) | ((unsigned)f2bf(h[3])<<16);
  o.z = (unsigned)f2bf(h[4]) | ((unsigned)f2bf(h[5])<<16);
  o.w = (unsigned)f2bf(h[6]) | ((unsigned)f2bf(h[7])<<16);
  *((uint4*)(hout + (size_t)wid*512) + lane) = o;
  if ((lane&15)==0) n4[(size_t)wid*4 + g] = qn;
}

// -------- fused 4-branch spmm layer1 (bf16 table, 512B/row) + post_spmm + Mobius combine --------
// xt: bf16 [N][4][64]; writes final output [N][64] f32
__global__ __launch_bounds__(256) void k_spmm_l1(const int* __restrict__ rowptr,
                        const int* __restrict__ srcs, const float4* __restrict__ wq,
                        const bfraw* __restrict__ xt,
                        float* __restrict__ out, int N){
  int wid = (blockIdx.x*blockDim.x + threadIdx.x)>>6;
  int lane = threadIdx.x & 63;
  if (wid >= N) return;
  int g = lane>>4;               // branch (16-lane groups, 4 dims/lane)
  int slot = lane & 15;
  float acc[4] = {0,0,0,0};
  int p0 = rowptr[wid], p1 = rowptr[wid+1];
  int p = p0;
  for (; p+4 <= p1; p += 4){
    int s0 = srcs[p], s1 = srcs[p+1], s2 = srcs[p+2], s3 = srcs[p+3];
    float4 w0 = wq[p], w1 = wq[p+1], w2 = wq[p+2], w3 = wq[p+3];
    uint2 u0 = *((const uint2*)(xt + (size_t)s0*256) + lane);
    uint2 u1 = *((const uint2*)(xt + (size_t)s1*256) + lane);
    uint2 u2 = *((const uint2*)(xt + (size_t)s2*256) + lane);
    uint2 u3 = *((const uint2*)(xt + (size_t)s3*256) + lane);
    acc4(acc, sel4(w0,g), u0);
    acc4(acc, sel4(w1,g), u1);
    acc4(acc, sel4(w2,g), u2);
    acc4(acc, sel4(w3,g), u3);
  }
  for (; p < p1; ++p){
    int s0 = srcs[p];
    float4 w0 = wq[p];
    uint2 u0 = *((const uint2*)(xt + (size_t)s0*256) + lane);
    acc4(acc, sel4(w0,g), u0);
  }
  // per-branch post_spmm chain (norms across 16-lane groups)
  float hv[4];
  float qn = postK<16,4>(acc, hv);
  // cross-branch gather: every lane collects all 4 branches' values for its dim slot
  float xk[4][4]; float qk[4];
  #pragma unroll
  for(int k=0;k<4;k++){
    #pragma unroll
    for(int j=0;j<4;j++) xk[k][j] = __shfl(hv[j], slot + 16*k, 64);
    qk[k] = __shfl(qn, 16*k, 64);
  }
  // target = chain of mobius_add(mobius_mulscaler(0.125, x_k))
  float xn0 = fmaxf(qk[0], 1e-15f);
  float s0 = tanhf(0.125f*artanh_c(xn0))/xn0;
  float t[4] = {s0*xk[0][0], s0*xk[0][1], s0*xk[0][2], s0*xk[0][3]};
  #pragma unroll
  for(int k=1;k<4;k++){
    float yn = fmaxf(qk[k], 1e-15f);
    float sy = tanhf(0.125f*artanh_c(yn))/yn;
    float y[4] = {sy*xk[k][0], sy*xk[k][1], sy*xk[k][2], sy*xk[k][3]};
    float dx=0.f, dy=0.f, dxy=0.f;
    #pragma unroll
    for(int j=0;j<4;j++){ dx += t[j]*t[j]; dy += y[j]*y[j]; dxy += t[j]*y[j]; }
    float x2 = gredw<16>(dx);
    float y2 = gredw<16>(dy);
    float xy = gredw<16>(dxy);
    float c1 = 1.f + 2.f*xy + y2;
    float c2 = 1.f - x2;
    float den = fmaxf(1.f + 2.f*xy + x2*y2, 1e-15f);
    #pragma unroll
    for(int j=0;j<4;j++) t[j] = (c1*t[j] + c2*y[j])/den;
  }
  // agg = mean of logmap0 over {x0..x3, t}
  float s[4] = {0,0,0,0};
  #pragma unroll
  for(int k=0;k<4;k++){
    float nk = fmaxf(qk[k], 1e-15f);
    float lk = artanh_c(nk)/nk;
    #pragma unroll
    for(int j=0;j<4;j++) s[j] = fmaf(lk, xk[k][j], s[j]);
  }
  float dt = 0.f;
  #pragma unroll
  for(int j=0;j<4;j++) dt += t[j]*t[j];
  float tn = fmaxf(sqrtf(gredw<16>(dt)), 1e-15f);
  float lt = artanh_c(tn)/tn;
  #pragma unroll
  for(int j=0;j<4;j++) s[j] = 0.2f*fmaf(lt, t[j], s[j]);
  // out = proj(expmap0(agg))
  float ds = 0.f;
  #pragma unroll
  for(int j=0;j<4;j++) ds += s[j]*s[j];
  float an = fmaxf(sqrtf(gredw<16>(ds)), 1e-15f);
  float on = tanhf(an);
  float osc = on/an;
  if (on > MAXN_P) osc *= MAXN_P/on;
  if (g == 0)
    *(float4*)(out + (size_t)wid*64 + 4*slot) =
      make_float4(s[0]*osc, s[1]*osc, s[2]*osc, s[3]*osc);
}

extern "C" void kernel_launch(void* const* d_in, const int* in_sizes, int n_in,
                              void* d_out, int out_size, void* d_ws, size_t ws_size,
                              hipStream_t stream){
  const float* x   = (const float*)d_in[0];
  const int*   src = (const int*)d_in[1];
  const int*   dst = (const int*)d_in[2];
  const float* ew  = (const float*)d_in[3];   // [4,E]
  const float* W0  = (const float*)d_in[4];   // [4,HID,128]
  const float* b0  = (const float*)d_in[5];   // [4,HID]
  const float* W1  = (const float*)d_in[6];   // [4,DIM,HID]
  const float* b1  = (const float*)d_in[7];   // [4,DIM]
  float* out = (float*)d_out;

  const int FIN = 128;
  int N = in_sizes[0]/FIN;
  int E = in_sizes[1];
  int HID = in_sizes[5]/4;   // 128
  int DIM = in_sizes[7]/4;   // 64

  char* ws = (char*)d_ws;
  size_t off = 0;
  auto alloc = [&](size_t bytes)->char*{
    char* p = ws + off;
    off += (bytes + 255) & ~(size_t)255;
    return p;
  };
  float* bufX   = (float*)alloc((size_t)N*4*FIN*4);   // 102.4 MB: GEMM outputs (both layers)
  bfraw* h4b    = (bfraw*)alloc((size_t)N*4*FIN*2);   // 51.2 MB: h4 bf16 (layer-1 GEMM A); prefix aliased as h0 f32
  bfraw* xtb    = (bfraw*)alloc((size_t)N*4*FIN*2);   // 51.2 MB: bf16 gather tables (l0 full, l1 half)
  float* n0     = (float*)alloc((size_t)N*4);
  float* n4     = (float*)alloc((size_t)N*16);
  int*   rowptr = (int*)alloc((size_t)(N+1)*4);
  int*   cnt    = (int*)alloc((size_t)N*4);
  int*   cursor = (int*)alloc((size_t)N*4);
  int*   srcs   = (int*)alloc((size_t)E*4);
  float4* wq    = (float4*)alloc((size_t)E*16);
  float* hb0    = (float*)alloc((size_t)4*HID*4);
  float* hb1    = (float*)alloc((size_t)4*DIM*4);
  (void)ws_size; (void)n_in; (void)out_size;

  // h0 [N,128] f32 aliases h4b's storage: h0 dead (after GEMM0) before spmm_l0 writes h4b
  float* h0 = (float*)h4b;

  int rowBlocks  = (N + 3)/4;      // wave per node
  int rowBlocks4 = N;              // wave per (node,branch)

  // CSR build (shared by both fused spmms); weights packed in CSR order
  hipMemsetAsync(cnt, 0, (size_t)N*4, stream);
  k_hist<<<(E+255)/256, 256, 0, stream>>>(dst, cnt, E);
  k_scan<<<1, 1024, 0, stream>>>(cnt, rowptr, cursor, N);
  k_fill<<<(E+255)/256, 256, 0, stream>>>(src, dst, ew, E, cursor, srcs, wq);

  // prologue
  k_exp0<<<rowBlocks, 256, 0, stream>>>(x, h0, n0, N);
  k_hb<<<8, 64, 0, stream>>>(b0, b1, hb0, hb1, HID, DIM);

  // layer 0: batched GEMM (f32 A) -> fused rowwise (bf16 out) -> fused spmm(+post, bf16 out)
  k_gemm<float><<<dim3((N+63)/64, HID/64, 4), 256, 0, stream>>>(h0, FIN, 0, W0, bufX, 4*HID, N, HID);
  k_post_gemm4<128><<<rowBlocks4, 256, 0, stream>>>(bufX, xtb, n0, 1, 0, hb0, N);
  k_spmm_l0<<<rowBlocks, 256, 0, stream>>>(rowptr, srcs, wq, xtb, h4b, n4, N);

  // layer 1: batched GEMM (bf16 A) -> fused rowwise (bf16 out) -> fused spmm(+post+combine) -> out
  k_gemm<bfraw><<<dim3((N+63)/64, DIM/64, 4), 256, 0, stream>>>(h4b, 4*HID, HID, W1, bufX, 4*DIM, N, DIM);
  k_post_gemm4<64><<<rowBlocks4, 256, 0, stream>>>(bufX, xtb, n4, 4, 1, hb1, N);
  k_spmm_l1<<<rowBlocks, 256, 0, stream>>>(rowptr, srcs, wq, xtb, out, N);
}

// Round 4
// 812.877 us; speedup vs baseline: 2.8492x; 1.3092x over previous
//
#include <hip/hip_runtime.h>
#include <math.h>

#define MAXN_P 0.996f   // (1 - PROJ_EPS)/sqrt(c), c=1

typedef unsigned short bfraw;
typedef __attribute__((ext_vector_type(8))) short bf16x8;
typedef __attribute__((ext_vector_type(4))) float f32x4;

__device__ __forceinline__ float wred(float v){
  #pragma unroll
  for(int o=32;o>0;o>>=1) v += __shfl_xor(v,o,64);
  return v;
}
template<int W>
__device__ __forceinline__ float gredw(float v){
  #pragma unroll
  for(int o=W/2;o>0;o>>=1) v += __shfl_xor(v,o,64);
  return v;
}
__device__ __forceinline__ float artanh_c(float x){
  x = fminf(fmaxf(x, -1.0f+1e-7f), 1.0f-1e-7f);
  return atanhf(x);
}
__device__ __forceinline__ float sel4(float4 w, int g){
  float ab = (g&1) ? w.y : w.x;
  float cd = (g&1) ? w.w : w.z;
  return (g&2) ? cd : ab;
}
__device__ __forceinline__ bfraw f2bf(float f){
  unsigned u = __float_as_uint(f);
  unsigned r = (u + 0x7fffu + ((u>>16)&1u)) >> 16;   // RNE
  return (bfraw)r;
}
__device__ __forceinline__ float bflo(unsigned u){ return __uint_as_float(u<<16); }
__device__ __forceinline__ float bfhi(unsigned u){ return __uint_as_float(u & 0xffff0000u); }

__device__ __forceinline__ void acc8(float* a, float w, uint4 u){
  a[0]=fmaf(w, bflo(u.x), a[0]); a[1]=fmaf(w, bfhi(u.x), a[1]);
  a[2]=fmaf(w, bflo(u.y), a[2]); a[3]=fmaf(w, bfhi(u.y), a[3]);
  a[4]=fmaf(w, bflo(u.z), a[4]); a[5]=fmaf(w, bfhi(u.z), a[5]);
  a[6]=fmaf(w, bflo(u.w), a[6]); a[7]=fmaf(w, bfhi(u.w), a[7]);
}
__device__ __forceinline__ void acc4(float* a, float w, uint2 u){
  a[0]=fmaf(w, bflo(u.x), a[0]); a[1]=fmaf(w, bfhi(u.x), a[1]);
  a[2]=fmaf(w, bflo(u.y), a[2]); a[3]=fmaf(w, bfhi(u.y), a[3]);
}

// post_spmm chain: u -> proj(expmap0(u)) -> relu(logmap0) -> proj(expmap0); norms over W lanes
template<int W, int K>
__device__ __forceinline__ float postK(const float* u, float* h){
  float ss = 0.f;
  #pragma unroll
  for(int k=0;k<K;k++) ss += u[k]*u[k];
  ss = gredw<W>(ss);
  float un = fmaxf(sqrtf(ss), 1e-15f);
  float t1 = tanhf(un);
  float sc = t1/un;
  float pn = t1;
  if (pn > MAXN_P){ sc *= MAXN_P/pn; pn = MAXN_P; }
  float ln = fmaxf(pn, 1e-15f);
  float m = sc * (artanh_c(ln)/ln);
  float v[K]; float vs = 0.f;
  #pragma unroll
  for(int k=0;k<K;k++){ v[k] = fmaxf(u[k]*m, 0.f); vs += v[k]*v[k]; }
  vs = gredw<W>(vs);
  float vn = fmaxf(sqrtf(vs), 1e-15f);
  float t2 = tanhf(vn);
  float qs = t2/vn;
  float qn = t2;
  if (qn > MAXN_P){ qs *= MAXN_P/qn; qn = MAXN_P; }
  #pragma unroll
  for(int k=0;k<K;k++) h[k] = v[k]*qs;
  return qn;
}

// ---------------- CSR build ----------------
__global__ void k_hist(const int* __restrict__ dst, int* __restrict__ cnt, int E){
  int e = blockIdx.x*blockDim.x + threadIdx.x;
  if (e < E) atomicAdd(&cnt[dst[e]], 1);
}

__global__ void k_scan(const int* __restrict__ cnt, int* __restrict__ rowptr,
                       int* __restrict__ cursor, int N){
  __shared__ int sh[1024];
  int t = threadIdx.x;
  int chunk = (N + 1023) / 1024;
  int b = t*chunk;
  int e = b + chunk; if (e > N) e = N;
  int s = 0;
  for(int i=b;i<e && i<N;i++) s += cnt[i];
  sh[t] = s;
  __syncthreads();
  for(int off=1; off<1024; off<<=1){
    int add = (t>=off) ? sh[t-off] : 0;
    __syncthreads();
    sh[t] += add;
    __syncthreads();
  }
  int run = (t==0) ? 0 : sh[t-1];
  for(int i=b;i<e && i<N;i++){
    rowptr[i] = run; cursor[i] = run; run += cnt[i];
  }
  if (t == 1023) rowptr[N] = run;
}

__global__ void k_fill(const int* __restrict__ src, const int* __restrict__ dst,
                       const float* __restrict__ ew, int E,
                       int* __restrict__ cursor, int* __restrict__ srcs,
                       float4* __restrict__ wq){
  int e = blockIdx.x*blockDim.x + threadIdx.x;
  if (e >= E) return;
  int d = dst[e];
  int pos = atomicAdd(&cursor[d], 1);
  srcs[pos] = src[e];
  wq[pos] = make_float4(ew[e], ew[(size_t)E + e], ew[2*(size_t)E + e], ew[3*(size_t)E + e]);
}

// ---------------- rowwise: h0 = proj(expmap0(x)) (bf16), n0 = ||h0|| ----------------
__global__ void k_exp0(const float* __restrict__ x, bfraw* __restrict__ h0,
                       float* __restrict__ n0, int N){
  int wid = (blockIdx.x*blockDim.x + threadIdx.x)>>6;
  int lane = threadIdx.x & 63;
  if (wid >= N) return;
  const float* r = x + (size_t)wid*128;
  float u0 = r[lane], u1 = r[lane+64];
  float ss = wred(u0*u0 + u1*u1);
  float un = fmaxf(sqrtf(ss), 1e-15f);
  float tn = tanhf(un);
  float sc = tn/un;
  float pn = tn;
  if (pn > MAXN_P){ sc *= MAXN_P/pn; pn = MAXN_P; }
  h0[(size_t)wid*128 + lane]      = f2bf(u0*sc);
  h0[(size_t)wid*128 + lane + 64] = f2bf(u1*sc);
  if (lane == 0) n0[wid] = pn;
}

// ---------------- hb = proj(expmap0(b)) for 4 branches x 2 layers ----------------
__global__ void k_hb(const float* __restrict__ b0, const float* __restrict__ b1,
                     float* __restrict__ hb0, float* __restrict__ hb1,
                     int HID, int DIM){
  int bl = blockIdx.x;       // 0..7
  int lane = threadIdx.x;    // 64
  int layer = bl >> 2, br = bl & 3;
  int D = layer ? DIM : HID;
  const float* b = layer ? (b1 + (size_t)br*DIM) : (b0 + (size_t)br*HID);
  float* o       = layer ? (hb1 + (size_t)br*DIM) : (hb0 + (size_t)br*HID);
  float v0 = (lane < D) ? b[lane] : 0.f;
  float v1 = (lane+64 < D) ? b[lane+64] : 0.f;
  float ss = wred(v0*v0 + v1*v1);
  float n = fmaxf(sqrtf(ss), 1e-15f);
  float tn = tanhf(n);
  float sc = tn/n;
  if (tn > MAXN_P) sc *= MAXN_P/tn;
  if (lane < D)    o[lane]    = v0*sc;
  if (lane+64 < D) o[lane+64] = v1*sc;
}

// ---------------- weights f32 -> bf16 ----------------
__global__ void k_w2bf(const float* __restrict__ a, bfraw* __restrict__ o, int n){
  int i = blockIdx.x*blockDim.x + threadIdx.x;
  if (i < n) o[i] = f2bf(a[i]);
}

// -------- MFMA bf16 GEMM (BM=64, BN=CT*16, K=128) + fused post_gemm epilogue --------
// C[node][J] = A[node]*W^T; then matvec-nl -> proj -> mobius_add(hb) -> proj -> logmap0
// writes bf16 xt[node][4][BN] for branch blockIdx.z
template<int CT>
__global__ __launch_bounds__(256) void k_gemm_fused(
    const bfraw* __restrict__ Abase, int lda, int abroff,
    const bfraw* __restrict__ Wb,          // [4][BN][128] bf16
    const float* __restrict__ nin, int nstride, int nbroff,
    const float* __restrict__ hball,       // [4][BN] f32
    bfraw* __restrict__ xt,                // [M][4][BN] bf16
    int M)
{
  constexpr int BN = CT*16;
  __shared__ bfraw tile[64*BN];
  int br = blockIdx.z;
  const bfraw* A = Abase + (size_t)br*abroff;
  const bfraw* W = Wb + (size_t)br*BN*128;
  const float* hb = hball + (size_t)br*BN;
  int rb = blockIdx.x*64;
  int t = threadIdx.x;
  int wave = t>>6, lane = t&63;
  int cl = lane&15, grp = lane>>4;

  // A fragments: lane holds row (rb+wave*16+cl), k = ks*32 + grp*8 .. +8
  int rowA = rb + wave*16 + cl;
  bf16x8 afr[4];
  bf16x8 zf = {0,0,0,0,0,0,0,0};
  #pragma unroll
  for(int ks=0;ks<4;ks++){
    if (rowA < M) afr[ks] = *(const bf16x8*)(A + (size_t)rowA*lda + ks*32 + grp*8);
    else          afr[ks] = zf;
  }
  f32x4 acc[CT];
  #pragma unroll
  for(int ct=0;ct<CT;ct++) acc[ct] = f32x4{0.f,0.f,0.f,0.f};
  #pragma unroll
  for(int ct=0;ct<CT;ct++){
    #pragma unroll
    for(int ks=0;ks<4;ks++){
      bf16x8 bfr = *(const bf16x8*)(W + (size_t)(ct*16+cl)*128 + ks*32 + grp*8);
      acc[ct] = __builtin_amdgcn_mfma_f32_16x16x32_bf16(afr[ks], bfr, acc[ct], 0,0,0);
    }
  }
  // epilogue: C layout col=lane&15, row=(lane>>4)*4+reg (per-wave 16-row stripe)
  float hv[CT]; float hb2 = 0.f;
  #pragma unroll
  for(int ct=0;ct<CT;ct++){ hv[ct] = hb[cl+16*ct]; hb2 += hv[ct]*hv[ct]; }
  hb2 = gredw<16>(hb2);
  #pragma unroll
  for(int j=0;j<4;j++){
    int rloc = wave*16 + grp*4 + j;
    int node = rb + rloc;
    bool v = node < M;
    float m[CT]; float ss = 0.f;
    #pragma unroll
    for(int ct=0;ct<CT;ct++){ m[ct] = acc[ct][j]; ss += m[ct]*m[ct]; }
    ss = gredw<16>(ss);
    float mxn_raw = sqrtf(ss);
    float mxn = fmaxf(mxn_raw, 1e-15f);
    float xn = fmaxf(v ? nin[(size_t)node*nstride + br*nbroff] : 1.f, 1e-15f);
    float th = tanhf(mxn/xn * artanh_c(xn));
    float hs = (mxn_raw > 0.f) ? th/mxn : 0.f;
    float hn = (mxn_raw > 0.f) ? th : 0.f;
    if (hn > MAXN_P){ hs *= MAXN_P/hn; hn = MAXN_P; }
    float h[CT]; float xy = 0.f, x2 = 0.f;
    #pragma unroll
    for(int ct=0;ct<CT;ct++){ h[ct] = m[ct]*hs; xy += h[ct]*hv[ct]; x2 += h[ct]*h[ct]; }
    xy = gredw<16>(xy); x2 = gredw<16>(x2);
    float c1 = 1.f + 2.f*xy + hb2;
    float c2 = 1.f - x2;
    float den = fmaxf(1.f + 2.f*xy + x2*hb2, 1e-15f);
    float a[CT]; float as = 0.f;
    #pragma unroll
    for(int ct=0;ct<CT;ct++){ a[ct] = (c1*h[ct] + c2*hv[ct])/den; as += a[ct]*a[ct]; }
    as = gredw<16>(as);
    float an = fmaxf(sqrtf(as), 1e-15f);
    float s2 = 1.f;
    if (an > MAXN_P){ s2 = MAXN_P/an; an = MAXN_P; }
    float ls = artanh_c(an)/an * s2;
    #pragma unroll
    for(int ct=0;ct<CT;ct++) tile[rloc*BN + cl + 16*ct] = f2bf(a[ct]*ls);
  }
  __syncthreads();
  constexpr int IT = (64*BN)/(256*8);
  #pragma unroll
  for(int i=0;i<IT;i++){
    int flat = (t + i*256)*8;
    int row = flat/BN, col = flat%BN;
    int node = rb + row;
    if (node < M)
      *(uint4*)(xt + ((size_t)node*4 + br)*BN + col) = *(const uint4*)(tile + row*BN + col);
  }
}

// -------- fused 4-branch spmm layer0 (bf16 table, 1KB/row) + post_spmm epilogue --------
__global__ __launch_bounds__(256) void k_spmm_l0(const int* __restrict__ rowptr,
                        const int* __restrict__ srcs, const float4* __restrict__ wq,
                        const bfraw* __restrict__ xt,
                        bfraw* __restrict__ hout, float* __restrict__ n4, int N){
  int wid = (blockIdx.x*blockDim.x + threadIdx.x)>>6;
  int lane = threadIdx.x & 63;
  if (wid >= N) return;
  int g = lane>>4;               // branch (16-lane groups, 8 dims/lane)
  float acc[8] = {0,0,0,0,0,0,0,0};
  int p0 = rowptr[wid], p1 = rowptr[wid+1];
  int p = p0;
  for (; p+4 <= p1; p += 4){
    int s0 = srcs[p], s1 = srcs[p+1], s2 = srcs[p+2], s3 = srcs[p+3];
    float4 w0 = wq[p], w1 = wq[p+1], w2 = wq[p+2], w3 = wq[p+3];
    uint4 u0 = *((const uint4*)(xt + (size_t)s0*512) + lane);
    uint4 u1 = *((const uint4*)(xt + (size_t)s1*512) + lane);
    uint4 u2 = *((const uint4*)(xt + (size_t)s2*512) + lane);
    uint4 u3 = *((const uint4*)(xt + (size_t)s3*512) + lane);
    acc8(acc, sel4(w0,g), u0);
    acc8(acc, sel4(w1,g), u1);
    acc8(acc, sel4(w2,g), u2);
    acc8(acc, sel4(w3,g), u3);
  }
  for (; p < p1; ++p){
    int s0 = srcs[p];
    float4 w0 = wq[p];
    uint4 u0 = *((const uint4*)(xt + (size_t)s0*512) + lane);
    acc8(acc, sel4(w0,g), u0);
  }
  float h[8];
  float qn = postK<16,8>(acc, h);
  uint4 o;
  o.x = (unsigned)f2bf(h[0]) | ((unsigned)f2bf(h[1])<<16);
  o.y = (unsigned)f2bf(h[2]) | ((unsigned)f2bf(h[3])<<16);
  o.z = (unsigned)f2bf(h[4]) | ((unsigned)f2bf(h[5])<<16);
  o.w = (unsigned)f2bf(h[6]) | ((unsigned)f2bf(h[7])<<16);
  *((uint4*)(hout + (size_t)wid*512) + lane) = o;
  if ((lane&15)==0) n4[(size_t)wid*4 + g] = qn;
}

// -------- fused 4-branch spmm layer1 (bf16 table, 512B/row) + post_spmm + Mobius combine --------
__global__ __launch_bounds__(256) void k_spmm_l1(const int* __restrict__ rowptr,
                        const int* __restrict__ srcs, const float4* __restrict__ wq,
                        const bfraw* __restrict__ xt,
                        float* __restrict__ out, int N){
  int wid = (blockIdx.x*blockDim.x + threadIdx.x)>>6;
  int lane = threadIdx.x & 63;
  if (wid >= N) return;
  int g = lane>>4;               // branch (16-lane groups, 4 dims/lane)
  int slot = lane & 15;
  float acc[4] = {0,0,0,0};
  int p0 = rowptr[wid], p1 = rowptr[wid+1];
  int p = p0;
  for (; p+4 <= p1; p += 4){
    int s0 = srcs[p], s1 = srcs[p+1], s2 = srcs[p+2], s3 = srcs[p+3];
    float4 w0 = wq[p], w1 = wq[p+1], w2 = wq[p+2], w3 = wq[p+3];
    uint2 u0 = *((const uint2*)(xt + (size_t)s0*256) + lane);
    uint2 u1 = *((const uint2*)(xt + (size_t)s1*256) + lane);
    uint2 u2 = *((const uint2*)(xt + (size_t)s2*256) + lane);
    uint2 u3 = *((const uint2*)(xt + (size_t)s3*256) + lane);
    acc4(acc, sel4(w0,g), u0);
    acc4(acc, sel4(w1,g), u1);
    acc4(acc, sel4(w2,g), u2);
    acc4(acc, sel4(w3,g), u3);
  }
  for (; p < p1; ++p){
    int s0 = srcs[p];
    float4 w0 = wq[p];
    uint2 u0 = *((const uint2*)(xt + (size_t)s0*256) + lane);
    acc4(acc, sel4(w0,g), u0);
  }
  float hv[4];
  float qn = postK<16,4>(acc, hv);
  float xk[4][4]; float qk[4];
  #pragma unroll
  for(int k=0;k<4;k++){
    #pragma unroll
    for(int j=0;j<4;j++) xk[k][j] = __shfl(hv[j], slot + 16*k, 64);
    qk[k] = __shfl(qn, 16*k, 64);
  }
  float xn0 = fmaxf(qk[0], 1e-15f);
  float s0 = tanhf(0.125f*artanh_c(xn0))/xn0;
  float t[4] = {s0*xk[0][0], s0*xk[0][1], s0*xk[0][2], s0*xk[0][3]};
  #pragma unroll
  for(int k=1;k<4;k++){
    float yn = fmaxf(qk[k], 1e-15f);
    float sy = tanhf(0.125f*artanh_c(yn))/yn;
    float y[4] = {sy*xk[k][0], sy*xk[k][1], sy*xk[k][2], sy*xk[k][3]};
    float dx=0.f, dy=0.f, dxy=0.f;
    #pragma unroll
    for(int j=0;j<4;j++){ dx += t[j]*t[j]; dy += y[j]*y[j]; dxy += t[j]*y[j]; }
    float x2 = gredw<16>(dx);
    float y2 = gredw<16>(dy);
    float xy = gredw<16>(dxy);
    float c1 = 1.f + 2.f*xy + y2;
    float c2 = 1.f - x2;
    float den = fmaxf(1.f + 2.f*xy + x2*y2, 1e-15f);
    #pragma unroll
    for(int j=0;j<4;j++) t[j] = (c1*t[j] + c2*y[j])/den;
  }
  float s[4] = {0,0,0,0};
  #pragma unroll
  for(int k=0;k<4;k++){
    float nk = fmaxf(qk[k], 1e-15f);
    float lk = artanh_c(nk)/nk;
    #pragma unroll
    for(int j=0;j<4;j++) s[j] = fmaf(lk, xk[k][j], s[j]);
  }
  float dt = 0.f;
  #pragma unroll
  for(int j=0;j<4;j++) dt += t[j]*t[j];
  float tn = fmaxf(sqrtf(gredw<16>(dt)), 1e-15f);
  float lt = artanh_c(tn)/tn;
  #pragma unroll
  for(int j=0;j<4;j++) s[j] = 0.2f*fmaf(lt, t[j], s[j]);
  float ds = 0.f;
  #pragma unroll
  for(int j=0;j<4;j++) ds += s[j]*s[j];
  float an = fmaxf(sqrtf(gredw<16>(ds)), 1e-15f);
  float on = tanhf(an);
  float osc = on/an;
  if (on > MAXN_P) osc *= MAXN_P/on;
  if (g == 0)
    *(float4*)(out + (size_t)wid*64 + 4*slot) =
      make_float4(s[0]*osc, s[1]*osc, s[2]*osc, s[3]*osc);
}

extern "C" void kernel_launch(void* const* d_in, const int* in_sizes, int n_in,
                              void* d_out, int out_size, void* d_ws, size_t ws_size,
                              hipStream_t stream){
  const float* x   = (const float*)d_in[0];
  const int*   src = (const int*)d_in[1];
  const int*   dst = (const int*)d_in[2];
  const float* ew  = (const float*)d_in[3];   // [4,E]
  const float* W0  = (const float*)d_in[4];   // [4,HID,128]
  const float* b0  = (const float*)d_in[5];   // [4,HID]
  const float* W1  = (const float*)d_in[6];   // [4,DIM,HID]
  const float* b1  = (const float*)d_in[7];   // [4,DIM]
  float* out = (float*)d_out;

  const int FIN = 128;
  int N = in_sizes[0]/FIN;
  int E = in_sizes[1];
  int HID = in_sizes[5]/4;   // 128
  int DIM = in_sizes[7]/4;   // 64

  char* ws = (char*)d_ws;
  size_t off = 0;
  auto alloc = [&](size_t bytes)->char*{
    char* p = ws + off;
    off += (bytes + 255) & ~(size_t)255;
    return p;
  };
  bfraw* h4b    = (bfraw*)alloc((size_t)N*4*FIN*2);   // 51.2 MB: h4 bf16; prefix aliased as h0 bf16
  bfraw* xtb    = (bfraw*)alloc((size_t)N*4*FIN*2);   // 51.2 MB: bf16 gather tables (l0 full, l1 half)
  float* n0     = (float*)alloc((size_t)N*4);
  float* n4     = (float*)alloc((size_t)N*16);
  int*   rowptr = (int*)alloc((size_t)(N+1)*4);
  int*   cnt    = (int*)alloc((size_t)N*4);
  int*   cursor = (int*)alloc((size_t)N*4);
  int*   srcs   = (int*)alloc((size_t)E*4);
  float4* wq    = (float4*)alloc((size_t)E*16);
  float* hb0    = (float*)alloc((size_t)4*HID*4);
  float* hb1    = (float*)alloc((size_t)4*DIM*4);
  bfraw* w0b    = (bfraw*)alloc((size_t)4*HID*FIN*2);
  bfraw* w1b    = (bfraw*)alloc((size_t)4*DIM*HID*2);
  (void)ws_size; (void)n_in; (void)out_size;

  // h0 bf16 [N,128] aliases h4b's storage: h0 dead (after GEMM0) before spmm_l0 writes h4b
  bfraw* h0 = h4b;

  int rowBlocks  = (N + 3)/4;      // wave per node

  // CSR build (shared by both fused spmms); weights packed in CSR order
  hipMemsetAsync(cnt, 0, (size_t)N*4, stream);
  k_hist<<<(E+255)/256, 256, 0, stream>>>(dst, cnt, E);
  k_scan<<<1, 1024, 0, stream>>>(cnt, rowptr, cursor, N);
  k_fill<<<(E+255)/256, 256, 0, stream>>>(src, dst, ew, E, cursor, srcs, wq);

  // prologue
  k_exp0<<<rowBlocks, 256, 0, stream>>>(x, h0, n0, N);
  k_hb<<<8, 64, 0, stream>>>(b0, b1, hb0, hb1, HID, DIM);
  k_w2bf<<<(4*HID*FIN+255)/256, 256, 0, stream>>>(W0, w0b, 4*HID*FIN);
  k_w2bf<<<(4*DIM*HID+255)/256, 256, 0, stream>>>(W1, w1b, 4*DIM*HID);

  // layer 0: MFMA GEMM + fused post (bf16 xt out) -> fused spmm(+post, bf16 out)
  k_gemm_fused<8><<<dim3((N+63)/64, 1, 4), 256, 0, stream>>>(
      h0, FIN, 0, w0b, n0, 1, 0, hb0, xtb, N);
  k_spmm_l0<<<rowBlocks, 256, 0, stream>>>(rowptr, srcs, wq, xtb, h4b, n4, N);

  // layer 1: MFMA GEMM + fused post (bf16 xt out) -> fused spmm(+post+combine) -> out
  k_gemm_fused<4><<<dim3((N+63)/64, 1, 4), 256, 0, stream>>>(
      h4b, 4*HID, HID, w1b, n4, 4, 1, hb1, xtb, N);
  k_spmm_l1<<<rowBlocks, 256, 0, stream>>>(rowptr, srcs, wq, xtb, out, N);
}

// Round 5
// 804.492 us; speedup vs baseline: 2.8789x; 1.0104x over previous
//
#include <hip/hip_runtime.h>
#include <math.h>

#define MAXN_P 0.996f   // (1 - PROJ_EPS)/sqrt(c), c=1

typedef unsigned short bfraw;
typedef __attribute__((ext_vector_type(8))) short bf16x8;
typedef __attribute__((ext_vector_type(4))) float f32x4;

__device__ __forceinline__ float wred(float v){
  #pragma unroll
  for(int o=32;o>0;o>>=1) v += __shfl_xor(v,o,64);
  return v;
}
template<int W>
__device__ __forceinline__ float gredw(float v){
  #pragma unroll
  for(int o=W/2;o>0;o>>=1) v += __shfl_xor(v,o,64);
  return v;
}
__device__ __forceinline__ float artanh_c(float x){
  x = fminf(fmaxf(x, -1.0f+1e-7f), 1.0f-1e-7f);
  return atanhf(x);
}
__device__ __forceinline__ float sel4(float4 w, int g){
  float ab = (g&1) ? w.y : w.x;
  float cd = (g&1) ? w.w : w.z;
  return (g&2) ? cd : ab;
}
__device__ __forceinline__ bfraw f2bf(float f){
  unsigned u = __float_as_uint(f);
  unsigned r = (u + 0x7fffu + ((u>>16)&1u)) >> 16;   // RNE
  return (bfraw)r;
}
__device__ __forceinline__ float bflo(unsigned u){ return __uint_as_float(u<<16); }
__device__ __forceinline__ float bfhi(unsigned u){ return __uint_as_float(u & 0xffff0000u); }

__device__ __forceinline__ void acc8(float* a, float w, uint4 u){
  a[0]=fmaf(w, bflo(u.x), a[0]); a[1]=fmaf(w, bfhi(u.x), a[1]);
  a[2]=fmaf(w, bflo(u.y), a[2]); a[3]=fmaf(w, bfhi(u.y), a[3]);
  a[4]=fmaf(w, bflo(u.z), a[4]); a[5]=fmaf(w, bfhi(u.z), a[5]);
  a[6]=fmaf(w, bflo(u.w), a[6]); a[7]=fmaf(w, bfhi(u.w), a[7]);
}
__device__ __forceinline__ void acc4(float* a, float w, uint2 u){
  a[0]=fmaf(w, bflo(u.x), a[0]); a[1]=fmaf(w, bfhi(u.x), a[1]);
  a[2]=fmaf(w, bflo(u.y), a[2]); a[3]=fmaf(w, bfhi(u.y), a[3]);
}

// post_spmm chain: u -> proj(expmap0(u)) -> relu(logmap0) -> proj(expmap0); norms over W lanes
template<int W, int K>
__device__ __forceinline__ float postK(const float* u, float* h){
  float ss = 0.f;
  #pragma unroll
  for(int k=0;k<K;k++) ss += u[k]*u[k];
  ss = gredw<W>(ss);
  float un = fmaxf(sqrtf(ss), 1e-15f);
  float t1 = tanhf(un);
  float sc = t1/un;
  float pn = t1;
  if (pn > MAXN_P){ sc *= MAXN_P/pn; pn = MAXN_P; }
  float ln = fmaxf(pn, 1e-15f);
  float m = sc * (artanh_c(ln)/ln);
  float v[K]; float vs = 0.f;
  #pragma unroll
  for(int k=0;k<K;k++){ v[k] = fmaxf(u[k]*m, 0.f); vs += v[k]*v[k]; }
  vs = gredw<W>(vs);
  float vn = fmaxf(sqrtf(vs), 1e-15f);
  float t2 = tanhf(vn);
  float qs = t2/vn;
  float qn = t2;
  if (qn > MAXN_P){ qs *= MAXN_P/qn; qn = MAXN_P; }
  #pragma unroll
  for(int k=0;k<K;k++) h[k] = v[k]*qs;
  return qn;
}

// ---------------- CSR build ----------------
__global__ void k_hist(const int* __restrict__ dst, int* __restrict__ cnt, int E){
  int e = blockIdx.x*blockDim.x + threadIdx.x;
  if (e < E) atomicAdd(&cnt[dst[e]], 1);
}

__global__ void k_scan(const int* __restrict__ cnt, int* __restrict__ rowptr,
                       int* __restrict__ cursor, int N){
  __shared__ int sh[1024];
  int t = threadIdx.x;
  int chunk = (N + 1023) / 1024;
  int b = t*chunk;
  int e = b + chunk; if (e > N) e = N;
  int s = 0;
  for(int i=b;i<e && i<N;i++) s += cnt[i];
  sh[t] = s;
  __syncthreads();
  for(int off=1; off<1024; off<<=1){
    int add = (t>=off) ? sh[t-off] : 0;
    __syncthreads();
    sh[t] += add;
    __syncthreads();
  }
  int run = (t==0) ? 0 : sh[t-1];
  for(int i=b;i<e && i<N;i++){
    rowptr[i] = run; cursor[i] = run; run += cnt[i];
  }
  if (t == 1023) rowptr[N] = run;
}

__global__ void k_fill(const int* __restrict__ src, const int* __restrict__ dst,
                       const float* __restrict__ ew, int E,
                       int* __restrict__ cursor, int* __restrict__ srcs,
                       float4* __restrict__ wq){
  int e = blockIdx.x*blockDim.x + threadIdx.x;
  if (e >= E) return;
  int d = dst[e];
  int pos = atomicAdd(&cursor[d], 1);
  srcs[pos] = src[e];
  wq[pos] = make_float4(ew[e], ew[(size_t)E + e], ew[2*(size_t)E + e], ew[3*(size_t)E + e]);
}

// ---------------- rowwise: h0 = proj(expmap0(x)) (bf16), n0 = ||h0|| ----------------
__global__ void k_exp0(const float* __restrict__ x, bfraw* __restrict__ h0,
                       float* __restrict__ n0, int N){
  int wid = (blockIdx.x*blockDim.x + threadIdx.x)>>6;
  int lane = threadIdx.x & 63;
  if (wid >= N) return;
  const float* r = x + (size_t)wid*128;
  float u0 = r[lane], u1 = r[lane+64];
  float ss = wred(u0*u0 + u1*u1);
  float un = fmaxf(sqrtf(ss), 1e-15f);
  float tn = tanhf(un);
  float sc = tn/un;
  float pn = tn;
  if (pn > MAXN_P){ sc *= MAXN_P/pn; pn = MAXN_P; }
  h0[(size_t)wid*128 + lane]      = f2bf(u0*sc);
  h0[(size_t)wid*128 + lane + 64] = f2bf(u1*sc);
  if (lane == 0) n0[wid] = pn;
}

// ---------------- hb = proj(expmap0(b)) for 4 branches x 2 layers ----------------
__global__ void k_hb(const float* __restrict__ b0, const float* __restrict__ b1,
                     float* __restrict__ hb0, float* __restrict__ hb1,
                     int HID, int DIM){
  int bl = blockIdx.x;       // 0..7
  int lane = threadIdx.x;    // 64
  int layer = bl >> 2, br = bl & 3;
  int D = layer ? DIM : HID;
  const float* b = layer ? (b1 + (size_t)br*DIM) : (b0 + (size_t)br*HID);
  float* o       = layer ? (hb1 + (size_t)br*DIM) : (hb0 + (size_t)br*HID);
  float v0 = (lane < D) ? b[lane] : 0.f;
  float v1 = (lane+64 < D) ? b[lane+64] : 0.f;
  float ss = wred(v0*v0 + v1*v1);
  float n = fmaxf(sqrtf(ss), 1e-15f);
  float tn = tanhf(n);
  float sc = tn/n;
  if (tn > MAXN_P) sc *= MAXN_P/tn;
  if (lane < D)    o[lane]    = v0*sc;
  if (lane+64 < D) o[lane+64] = v1*sc;
}

// ---------------- weights f32 -> bf16 ----------------
__global__ void k_w2bf(const float* __restrict__ a, bfraw* __restrict__ o, int n){
  int i = blockIdx.x*blockDim.x + threadIdx.x;
  if (i < n) o[i] = f2bf(a[i]);
}

// -------- MFMA bf16 GEMM (BM=64, BN=CT*16, K=128) + fused post_gemm epilogue --------
template<int CT>
__global__ __launch_bounds__(256) void k_gemm_fused(
    const bfraw* __restrict__ Abase, int lda, int abroff,
    const bfraw* __restrict__ Wb,          // [4][BN][128] bf16
    const float* __restrict__ nin, int nstride, int nbroff,
    const float* __restrict__ hball,       // [4][BN] f32
    bfraw* __restrict__ xt,                // [M][4][BN] bf16
    int M)
{
  constexpr int BN = CT*16;
  __shared__ bfraw tile[64*BN];
  int br = blockIdx.z;
  const bfraw* A = Abase + (size_t)br*abroff;
  const bfraw* W = Wb + (size_t)br*BN*128;
  const float* hb = hball + (size_t)br*BN;
  int rb = blockIdx.x*64;
  int t = threadIdx.x;
  int wave = t>>6, lane = t&63;
  int cl = lane&15, grp = lane>>4;

  int rowA = rb + wave*16 + cl;
  bf16x8 afr[4];
  bf16x8 zf = {0,0,0,0,0,0,0,0};
  #pragma unroll
  for(int ks=0;ks<4;ks++){
    if (rowA < M) afr[ks] = *(const bf16x8*)(A + (size_t)rowA*lda + ks*32 + grp*8);
    else          afr[ks] = zf;
  }
  f32x4 acc[CT];
  #pragma unroll
  for(int ct=0;ct<CT;ct++) acc[ct] = f32x4{0.f,0.f,0.f,0.f};
  #pragma unroll
  for(int ct=0;ct<CT;ct++){
    #pragma unroll
    for(int ks=0;ks<4;ks++){
      bf16x8 bfr = *(const bf16x8*)(W + (size_t)(ct*16+cl)*128 + ks*32 + grp*8);
      acc[ct] = __builtin_amdgcn_mfma_f32_16x16x32_bf16(afr[ks], bfr, acc[ct], 0,0,0);
    }
  }
  float hv[CT]; float hb2 = 0.f;
  #pragma unroll
  for(int ct=0;ct<CT;ct++){ hv[ct] = hb[cl+16*ct]; hb2 += hv[ct]*hv[ct]; }
  hb2 = gredw<16>(hb2);
  #pragma unroll
  for(int j=0;j<4;j++){
    int rloc = wave*16 + grp*4 + j;
    int node = rb + rloc;
    bool v = node < M;
    float m[CT]; float ss = 0.f;
    #pragma unroll
    for(int ct=0;ct<CT;ct++){ m[ct] = acc[ct][j]; ss += m[ct]*m[ct]; }
    ss = gredw<16>(ss);
    float mxn_raw = sqrtf(ss);
    float mxn = fmaxf(mxn_raw, 1e-15f);
    float xn = fmaxf(v ? nin[(size_t)node*nstride + br*nbroff] : 1.f, 1e-15f);
    float th = tanhf(mxn/xn * artanh_c(xn));
    float hs = (mxn_raw > 0.f) ? th/mxn : 0.f;
    float hn = (mxn_raw > 0.f) ? th : 0.f;
    if (hn > MAXN_P){ hs *= MAXN_P/hn; hn = MAXN_P; }
    float h[CT]; float xy = 0.f, x2 = 0.f;
    #pragma unroll
    for(int ct=0;ct<CT;ct++){ h[ct] = m[ct]*hs; xy += h[ct]*hv[ct]; x2 += h[ct]*h[ct]; }
    xy = gredw<16>(xy); x2 = gredw<16>(x2);
    float c1 = 1.f + 2.f*xy + hb2;
    float c2 = 1.f - x2;
    float den = fmaxf(1.f + 2.f*xy + x2*hb2, 1e-15f);
    float a[CT]; float as = 0.f;
    #pragma unroll
    for(int ct=0;ct<CT;ct++){ a[ct] = (c1*h[ct] + c2*hv[ct])/den; as += a[ct]*a[ct]; }
    as = gredw<16>(as);
    float an = fmaxf(sqrtf(as), 1e-15f);
    float s2 = 1.f;
    if (an > MAXN_P){ s2 = MAXN_P/an; an = MAXN_P; }
    float ls = artanh_c(an)/an * s2;
    #pragma unroll
    for(int ct=0;ct<CT;ct++) tile[rloc*BN + cl + 16*ct] = f2bf(a[ct]*ls);
  }
  __syncthreads();
  constexpr int IT = (64*BN)/(256*8);
  #pragma unroll
  for(int i=0;i<IT;i++){
    int flat = (t + i*256)*8;
    int row = flat/BN, col = flat%BN;
    int node = rb + row;
    if (node < M)
      *(uint4*)(xt + ((size_t)node*4 + br)*BN + col) = *(const uint4*)(tile + row*BN + col);
  }
}

// -------- fused 4-branch spmm layer0 (bf16 table, 1KB/row, 8-deep gather pipeline) --------
__global__ __launch_bounds__(256) void k_spmm_l0(const int* __restrict__ rowptr,
                        const int* __restrict__ srcs, const float4* __restrict__ wq,
                        const bfraw* __restrict__ xt,
                        bfraw* __restrict__ hout, float* __restrict__ n4, int N){
  int wid = (blockIdx.x*blockDim.x + threadIdx.x)>>6;
  int lane = threadIdx.x & 63;
  if (wid >= N) return;
  int g = lane>>4;               // branch (16-lane groups, 8 dims/lane)
  float acc[8] = {0,0,0,0,0,0,0,0};
  int p0 = rowptr[wid], p1 = rowptr[wid+1];
  int p = p0;
  for (; p+8 <= p1; p += 8){
    int s[8]; float4 w[8]; uint4 u[8];
    #pragma unroll
    for(int i=0;i<8;i++){ s[i] = srcs[p+i]; w[i] = wq[p+i]; }
    #pragma unroll
    for(int i=0;i<8;i++) u[i] = *((const uint4*)(xt + (size_t)s[i]*512) + lane);
    #pragma unroll
    for(int i=0;i<8;i++) acc8(acc, sel4(w[i],g), u[i]);
  }
  for (; p+2 <= p1; p += 2){
    int s0 = srcs[p], s1 = srcs[p+1];
    float4 w0 = wq[p], w1 = wq[p+1];
    uint4 u0 = *((const uint4*)(xt + (size_t)s0*512) + lane);
    uint4 u1 = *((const uint4*)(xt + (size_t)s1*512) + lane);
    acc8(acc, sel4(w0,g), u0);
    acc8(acc, sel4(w1,g), u1);
  }
  if (p < p1){
    int s0 = srcs[p];
    float4 w0 = wq[p];
    uint4 u0 = *((const uint4*)(xt + (size_t)s0*512) + lane);
    acc8(acc, sel4(w0,g), u0);
  }
  float h[8];
  float qn = postK<16,8>(acc, h);
  uint4 o;
  o.x = (unsigned)f2bf(h[0]) | ((unsigned)f2bf(h[1])<<16);
  o.y = (unsigned)f2bf(h[2]) | ((unsigned)f2bf(h[3])<<16);
  o.z = (unsigned)f2bf(h[4]) | ((unsigned)f2bf(h[5])<<16);
  o.w = (unsigned)f2bf(h[6]) | ((unsigned)f2bf(h[7])<<16);
  *((uint4*)(hout + (size_t)wid*512) + lane) = o;
  if ((lane&15)==0) n4[(size_t)wid*4 + g] = qn;
}

// -------- fused 4-branch spmm layer1 (bf16, 512B/row, 8-deep) + post + Mobius combine --------
__global__ __launch_bounds__(256) void k_spmm_l1(const int* __restrict__ rowptr,
                        const int* __restrict__ srcs, const float4* __restrict__ wq,
                        const bfraw* __restrict__ xt,
                        float* __restrict__ out, int N){
  int wid = (blockIdx.x*blockDim.x + threadIdx.x)>>6;
  int lane = threadIdx.x & 63;
  if (wid >= N) return;
  int g = lane>>4;               // branch (16-lane groups, 4 dims/lane)
  int slot = lane & 15;
  float acc[4] = {0,0,0,0};
  int p0 = rowptr[wid], p1 = rowptr[wid+1];
  int p = p0;
  for (; p+8 <= p1; p += 8){
    int s[8]; float4 w[8]; uint2 u[8];
    #pragma unroll
    for(int i=0;i<8;i++){ s[i] = srcs[p+i]; w[i] = wq[p+i]; }
    #pragma unroll
    for(int i=0;i<8;i++) u[i] = *((const uint2*)(xt + (size_t)s[i]*256) + lane);
    #pragma unroll
    for(int i=0;i<8;i++) acc4(acc, sel4(w[i],g), u[i]);
  }
  for (; p+2 <= p1; p += 2){
    int s0 = srcs[p], s1 = srcs[p+1];
    float4 w0 = wq[p], w1 = wq[p+1];
    uint2 u0 = *((const uint2*)(xt + (size_t)s0*256) + lane);
    uint2 u1 = *((const uint2*)(xt + (size_t)s1*256) + lane);
    acc4(acc, sel4(w0,g), u0);
    acc4(acc, sel4(w1,g), u1);
  }
  if (p < p1){
    int s0 = srcs[p];
    float4 w0 = wq[p];
    uint2 u0 = *((const uint2*)(xt + (size_t)s0*256) + lane);
    acc4(acc, sel4(w0,g), u0);
  }
  float hv[4];
  float qn = postK<16,4>(acc, hv);
  float xk[4][4]; float qk[4];
  #pragma unroll
  for(int k=0;k<4;k++){
    #pragma unroll
    for(int j=0;j<4;j++) xk[k][j] = __shfl(hv[j], slot + 16*k, 64);
    qk[k] = __shfl(qn, 16*k, 64);
  }
  float xn0 = fmaxf(qk[0], 1e-15f);
  float s0 = tanhf(0.125f*artanh_c(xn0))/xn0;
  float t[4] = {s0*xk[0][0], s0*xk[0][1], s0*xk[0][2], s0*xk[0][3]};
  #pragma unroll
  for(int k=1;k<4;k++){
    float yn = fmaxf(qk[k], 1e-15f);
    float sy = tanhf(0.125f*artanh_c(yn))/yn;
    float y[4] = {sy*xk[k][0], sy*xk[k][1], sy*xk[k][2], sy*xk[k][3]};
    float dx=0.f, dy=0.f, dxy=0.f;
    #pragma unroll
    for(int j=0;j<4;j++){ dx += t[j]*t[j]; dy += y[j]*y[j]; dxy += t[j]*y[j]; }
    float x2 = gredw<16>(dx);
    float y2 = gredw<16>(dy);
    float xy = gredw<16>(dxy);
    float c1 = 1.f + 2.f*xy + y2;
    float c2 = 1.f - x2;
    float den = fmaxf(1.f + 2.f*xy + x2*y2, 1e-15f);
    #pragma unroll
    for(int j=0;j<4;j++) t[j] = (c1*t[j] + c2*y[j])/den;
  }
  float s[4] = {0,0,0,0};
  #pragma unroll
  for(int k=0;k<4;k++){
    float nk = fmaxf(qk[k], 1e-15f);
    float lk = artanh_c(nk)/nk;
    #pragma unroll
    for(int j=0;j<4;j++) s[j] = fmaf(lk, xk[k][j], s[j]);
  }
  float dt = 0.f;
  #pragma unroll
  for(int j=0;j<4;j++) dt += t[j]*t[j];
  float tn = fmaxf(sqrtf(gredw<16>(dt)), 1e-15f);
  float lt = artanh_c(tn)/tn;
  #pragma unroll
  for(int j=0;j<4;j++) s[j] = 0.2f*fmaf(lt, t[j], s[j]);
  float ds = 0.f;
  #pragma unroll
  for(int j=0;j<4;j++) ds += s[j]*s[j];
  float an = fmaxf(sqrtf(gredw<16>(ds)), 1e-15f);
  float on = tanhf(an);
  float osc = on/an;
  if (on > MAXN_P) osc *= MAXN_P/on;
  if (g == 0)
    *(float4*)(out + (size_t)wid*64 + 4*slot) =
      make_float4(s[0]*osc, s[1]*osc, s[2]*osc, s[3]*osc);
}

extern "C" void kernel_launch(void* const* d_in, const int* in_sizes, int n_in,
                              void* d_out, int out_size, void* d_ws, size_t ws_size,
                              hipStream_t stream){
  const float* x   = (const float*)d_in[0];
  const int*   src = (const int*)d_in[1];
  const int*   dst = (const int*)d_in[2];
  const float* ew  = (const float*)d_in[3];   // [4,E]
  const float* W0  = (const float*)d_in[4];   // [4,HID,128]
  const float* b0  = (const float*)d_in[5];   // [4,HID]
  const float* W1  = (const float*)d_in[6];   // [4,DIM,HID]
  const float* b1  = (const float*)d_in[7];   // [4,DIM]
  float* out = (float*)d_out;

  const int FIN = 128;
  int N = in_sizes[0]/FIN;
  int E = in_sizes[1];
  int HID = in_sizes[5]/4;   // 128
  int DIM = in_sizes[7]/4;   // 64

  char* ws = (char*)d_ws;
  size_t off = 0;
  auto alloc = [&](size_t bytes)->char*{
    char* p = ws + off;
    off += (bytes + 255) & ~(size_t)255;
    return p;
  };
  bfraw* h4b    = (bfraw*)alloc((size_t)N*4*FIN*2);   // h4 bf16; prefix aliased as h0 bf16
  bfraw* xtb    = (bfraw*)alloc((size_t)N*4*FIN*2);   // bf16 gather tables (l0 full, l1 half)
  float* n0     = (float*)alloc((size_t)N*4);
  float* n4     = (float*)alloc((size_t)N*16);
  int*   rowptr = (int*)alloc((size_t)(N+1)*4);
  int*   cnt    = (int*)alloc((size_t)N*4);
  int*   cursor = (int*)alloc((size_t)N*4);
  int*   srcs   = (int*)alloc((size_t)E*4);
  float4* wq    = (float4*)alloc((size_t)E*16);
  float* hb0    = (float*)alloc((size_t)4*HID*4);
  float* hb1    = (float*)alloc((size_t)4*DIM*4);
  bfraw* w0b    = (bfraw*)alloc((size_t)4*HID*FIN*2);
  bfraw* w1b    = (bfraw*)alloc((size_t)4*DIM*HID*2);
  (void)ws_size; (void)n_in; (void)out_size;

  bfraw* h0 = h4b;   // h0 dead (after GEMM0) before spmm_l0 writes h4b

  int rowBlocks  = (N + 3)/4;      // wave per node

  // CSR build (shared by both fused spmms); weights packed in CSR order
  hipMemsetAsync(cnt, 0, (size_t)N*4, stream);
  k_hist<<<(E+255)/256, 256, 0, stream>>>(dst, cnt, E);
  k_scan<<<1, 1024, 0, stream>>>(cnt, rowptr, cursor, N);
  k_fill<<<(E+255)/256, 256, 0, stream>>>(src, dst, ew, E, cursor, srcs, wq);

  // prologue
  k_exp0<<<rowBlocks, 256, 0, stream>>>(x, h0, n0, N);
  k_hb<<<8, 64, 0, stream>>>(b0, b1, hb0, hb1, HID, DIM);
  k_w2bf<<<(4*HID*FIN+255)/256, 256, 0, stream>>>(W0, w0b, 4*HID*FIN);
  k_w2bf<<<(4*DIM*HID+255)/256, 256, 0, stream>>>(W1, w1b, 4*DIM*HID);

  // layer 0: MFMA GEMM + fused post (bf16 xt out) -> fused spmm(+post, bf16 out)
  k_gemm_fused<8><<<dim3((N+63)/64, 1, 4), 256, 0, stream>>>(
      h0, FIN, 0, w0b, n0, 1, 0, hb0, xtb, N);
  k_spmm_l0<<<rowBlocks, 256, 0, stream>>>(rowptr, srcs, wq, xtb, h4b, n4, N);

  // layer 1: MFMA GEMM + fused post (bf16 xt out) -> fused spmm(+post+combine) -> out
  k_gemm_fused<4><<<dim3((N+63)/64, 1, 4), 256, 0, stream>>>(
      h4b, 4*HID, HID, w1b, n4, 4, 1, hb1, xtb, N);
  k_spmm_l1<<<rowBlocks, 256, 0, stream>>>(rowptr, srcs, wq, xtb, out, N);
}